// Round 4
// baseline (715.053 us; speedup 1.0000x reference)
//
#include <hip/hip_runtime.h>
#include <hip/hip_bf16.h>

// GCN: 2x GraphConv(norm='both') + per-graph mean + [hg|perm] @ Wc + bc
// N=100000, E=1600000, D=H=128, P=64, C=10, G=128

#define BUCKET_CAP 64
#define OVF_CAP 4096
#define NUM_G 128
#define NPASS 8

// ---- out-degree histogram (vectorized, 400 KB counter array stays cached) ----
__global__ void outdeg_kernel(const int* __restrict__ src, int E, int* __restrict__ outdeg) {
    int t = blockIdx.x * blockDim.x + threadIdx.x;
    int e0 = t * 4;
    if (e0 + 3 < E) {
        int4 s4 = *(const int4*)(src + e0);
        atomicAdd(&outdeg[s4.x], 1);
        atomicAdd(&outdeg[s4.y], 1);
        atomicAdd(&outdeg[s4.z], 1);
        atomicAdd(&outdeg[s4.w], 1);
    } else {
        for (int e = e0; e < E; e++) atomicAdd(&outdeg[src[e]], 1);
    }
}

// ---- partitioned bucket build: only dst in [lo,hi) processed this pass ----
// Window = N/NPASS nodes -> 3.2 MB bucket region: a node's writes cluster in
// time, lines evict once (fixes the 146 MB write amplification seen in R3).
__global__ void build_pass_kernel(const int* __restrict__ src, const int* __restrict__ dst,
                                  int E, int lo, int hi,
                                  int* __restrict__ indeg, int* __restrict__ bucket,
                                  int* __restrict__ ovfc, int* __restrict__ ovfl) {
    int t = blockIdx.x * blockDim.x + threadIdx.x;
    int e0 = t * 4;
    if (e0 >= E) return;
    int d[4];
    int nv = (e0 + 3 < E) ? 4 : (E - e0);
    if (nv == 4) {
        int4 d4 = *(const int4*)(dst + e0);
        d[0] = d4.x; d[1] = d4.y; d[2] = d4.z; d[3] = d4.w;
    } else {
        for (int i = 0; i < nv; i++) d[i] = dst[e0 + i];
    }
#pragma unroll
    for (int i = 0; i < 4; i++) {
        if (i >= nv) break;
        int di = d[i];
        if (di < lo || di >= hi) continue;
        int s = src[e0 + i];
        int slot = atomicAdd(&indeg[di], 1);
        if (slot < BUCKET_CAP) {
            bucket[(size_t)di * BUCKET_CAP + slot] = s;
        } else {
            int p = atomicAdd(ovfc, 1);
            if (p < OVF_CAP) ovfl[p] = e0 + i;
        }
    }
}

// ---- graph_ids sorted -> segment offsets by boundary detection (NO atomics) ----
__global__ void goffs_kernel(const int* __restrict__ gids, int N, int* __restrict__ goffs) {
    int i = blockIdx.x * blockDim.x + threadIdx.x;
    if (i > N) return;
    int prev = (i == 0) ? -1 : gids[i - 1];
    int cur  = (i == N) ? NUM_G : gids[i];
    for (int g = prev + 1; g <= cur && g <= NUM_G; g++) goffs[g] = i;
}

// ---- degree -> rsqrt norms ----
__global__ void norm_kernel(const int* __restrict__ outdeg, const int* __restrict__ indeg,
                            float* __restrict__ nrm_out, float* __restrict__ nrm_in, int N) {
    int i = blockIdx.x * blockDim.x + threadIdx.x;
    if (i >= N) return;
    nrm_out[i] = rsqrtf(fmaxf((float)outdeg[i], 1.0f));
    nrm_in[i]  = rsqrtf(fmaxf((float)indeg[i], 1.0f));
}

// ---- xs[n] = h[n] * nrm_out[n]  (pre-scale so agg is a pure gather-sum) ----
__global__ void scale_kernel(const float* __restrict__ h, const float* __restrict__ nrm_out,
                             float* __restrict__ xs, int N) {
    int t = blockIdx.x * blockDim.x + threadIdx.x;
    int node = t >> 5, q = t & 31;
    if (node >= N) return;
    float ns = nrm_out[node];
    float4 v = ((const float4*)h)[(size_t)node * 32 + q];
    v.x *= ns; v.y *= ns; v.z *= ns; v.w *= ns;
    ((float4*)xs)[(size_t)node * 32 + q] = v;
}

// ---- aggregation: one 32-lane group per node, float4 per lane, no atomics ----
__global__ void agg_kernel(const float* __restrict__ x,
                           const int* __restrict__ bucket, const int* __restrict__ indeg,
                           float* __restrict__ agg, int N) {
    int t = blockIdx.x * blockDim.x + threadIdx.x;
    int node = t >> 5;
    int q = t & 31;
    if (node >= N) return;
    int deg = indeg[node];
    if (deg > BUCKET_CAP) deg = BUCKET_CAP;
    const int* bk = bucket + (size_t)node * BUCKET_CAP;
    float4 acc = make_float4(0.f, 0.f, 0.f, 0.f);
    for (int j = 0; j < deg; j++) {
        int s = bk[j];
        float4 v = ((const float4*)x)[(size_t)s * 32 + q];
        acc.x += v.x; acc.y += v.y; acc.z += v.z; acc.w += v.w;
    }
    ((float4*)agg)[(size_t)node * 32 + q] = acc;
}

// ---- rare bucket-overflow edges: atomic fallback (x already pre-scaled) ----
__global__ void ovf_kernel(const float* __restrict__ x,
                           const int* __restrict__ src, const int* __restrict__ dst,
                           const int* __restrict__ ovfc, const int* __restrict__ ovfl,
                           float* __restrict__ agg) {
    int t = blockIdx.x * blockDim.x + threadIdx.x;
    int idx = t >> 5, q = t & 31;
    int n = *ovfc;
    if (n > OVF_CAP) n = OVF_CAP;
    if (idx >= n) return;
    int e = ovfl[idx];
    int s = src[e], d = dst[e];
    float4 v = ((const float4*)x)[(size_t)s * 32 + q];
    float* ap = agg + (size_t)d * 128 + q * 4;
    atomicAdd(ap + 0, v.x);
    atomicAdd(ap + 1, v.y);
    atomicAdd(ap + 2, v.z);
    atomicAdd(ap + 3, v.w);
}

// ---- out[r][c] = act(rowscale[r] * sum_k A[r][k]*W[k][c] + bias[c]) [*post[r]] ----
// W (128x128) fully in LDS. 256 threads: 64 row-pairs x 4 col-groups.
// Safe to run IN-PLACE (out==A): each thread exclusively owns its 2 rows and
// all its loads precede its stores via the acc data dependence.
__global__ __launch_bounds__(256) void gemm128(const float* A,
                                               const float* __restrict__ W,
                                               const float* __restrict__ bias,
                                               const float* __restrict__ rowscale,
                                               const float* __restrict__ postscale,
                                               float* out, int N, int do_relu) {
    __shared__ float Wl[128 * 128];
    for (int i = threadIdx.x; i < 4096; i += 256)
        ((float4*)Wl)[i] = ((const float4*)W)[i];
    __syncthreads();

    int gi = threadIdx.x & 3;
    int rp = threadIdx.x >> 2;
    int r0 = blockIdx.x * 128 + rp * 2;
    if (r0 >= N) return;
    bool two = (r0 + 1 < N);

    const float* A0 = A + (size_t)r0 * 128;
    const float* A1 = two ? (A0 + 128) : A0;

    float acc0[32], acc1[32];
#pragma unroll
    for (int j = 0; j < 32; j++) { acc0[j] = 0.f; acc1[j] = 0.f; }

    for (int k4 = 0; k4 < 32; k4++) {
        float4 a0 = ((const float4*)A0)[k4];
        float4 a1 = ((const float4*)A1)[k4];
#pragma unroll
        for (int kk = 0; kk < 4; kk++) {
            int k = k4 * 4 + kk;
            float av0 = (kk == 0) ? a0.x : (kk == 1) ? a0.y : (kk == 2) ? a0.z : a0.w;
            float av1 = (kk == 0) ? a1.x : (kk == 1) ? a1.y : (kk == 2) ? a1.z : a1.w;
            const float* wrow = Wl + k * 128 + gi * 4;
#pragma unroll
            for (int m = 0; m < 8; m++) {
                float4 wv = *(const float4*)(wrow + m * 16);
                acc0[m * 4 + 0] = fmaf(av0, wv.x, acc0[m * 4 + 0]);
                acc0[m * 4 + 1] = fmaf(av0, wv.y, acc0[m * 4 + 1]);
                acc0[m * 4 + 2] = fmaf(av0, wv.z, acc0[m * 4 + 2]);
                acc0[m * 4 + 3] = fmaf(av0, wv.w, acc0[m * 4 + 3]);
                acc1[m * 4 + 0] = fmaf(av1, wv.x, acc1[m * 4 + 0]);
                acc1[m * 4 + 1] = fmaf(av1, wv.y, acc1[m * 4 + 1]);
                acc1[m * 4 + 2] = fmaf(av1, wv.z, acc1[m * 4 + 2]);
                acc1[m * 4 + 3] = fmaf(av1, wv.w, acc1[m * 4 + 3]);
            }
        }
    }

    float s0 = rowscale[r0];
    float s1 = two ? rowscale[r0 + 1] : 0.f;
    float p0 = 1.f, p1 = 1.f;
    if (postscale) {
        p0 = postscale[r0];
        p1 = two ? postscale[r0 + 1] : 0.f;
    }
    float* o0 = out + (size_t)r0 * 128;
#pragma unroll
    for (int m = 0; m < 8; m++) {
        int c = m * 16 + gi * 4;
        float4 b4 = *(const float4*)(bias + c);
        float4 v0, v1;
        v0.x = fmaf(s0, acc0[m * 4 + 0], b4.x);
        v0.y = fmaf(s0, acc0[m * 4 + 1], b4.y);
        v0.z = fmaf(s0, acc0[m * 4 + 2], b4.z);
        v0.w = fmaf(s0, acc0[m * 4 + 3], b4.w);
        if (do_relu) {
            v0.x = fmaxf(v0.x, 0.f); v0.y = fmaxf(v0.y, 0.f);
            v0.z = fmaxf(v0.z, 0.f); v0.w = fmaxf(v0.w, 0.f);
        }
        v0.x *= p0; v0.y *= p0; v0.z *= p0; v0.w *= p0;
        *(float4*)(o0 + c) = v0;
        if (two) {
            v1.x = fmaf(s1, acc1[m * 4 + 0], b4.x);
            v1.y = fmaf(s1, acc1[m * 4 + 1], b4.y);
            v1.z = fmaf(s1, acc1[m * 4 + 2], b4.z);
            v1.w = fmaf(s1, acc1[m * 4 + 3], b4.w);
            if (do_relu) {
                v1.x = fmaxf(v1.x, 0.f); v1.y = fmaxf(v1.y, 0.f);
                v1.z = fmaxf(v1.z, 0.f); v1.w = fmaxf(v1.w, 0.f);
            }
            v1.x *= p1; v1.y *= p1; v1.z *= p1; v1.w *= p1;
            *(float4*)(o0 + 128 + c) = v1;
        }
    }
}

// ---- per-graph mean: block per graph, 8 row-lanes x 128 cols + LDS reduce ----
__global__ __launch_bounds__(1024) void mean_kernel(const float* __restrict__ x2,
                                                    const int* __restrict__ goffs,
                                                    float* __restrict__ hg) {
    __shared__ float red[8][128];
    int g = blockIdx.x;
    int c = threadIdx.x & 127;
    int j = threadIdx.x >> 7;  // 0..7
    int s = goffs[g], e = goffs[g + 1];
    float acc = 0.f;
    for (int r = s + j; r < e; r += 8) acc += x2[(size_t)r * 128 + c];
    red[j][c] = acc;
    __syncthreads();
    if (j == 0) {
        float t = red[0][c];
#pragma unroll
        for (int jj = 1; jj < 8; jj++) t += red[jj][c];
        float cnt = fmaxf((float)(e - s), 1.0f);
        hg[g * 128 + c] = t / cnt;
    }
}

// ---- classifier head: [G,128|64] @ Wc[192,10] + bc ----
__global__ void final_kernel(const float* __restrict__ hg, const float* __restrict__ perm,
                             const float* __restrict__ Wc, const float* __restrict__ bc,
                             float* __restrict__ out, int G) {
    int t = blockIdx.x * blockDim.x + threadIdx.x;
    if (t >= G * 10) return;
    int g = t / 10, c = t % 10;
    float acc = bc[c];
    const float* hrow = hg + g * 128;
#pragma unroll 8
    for (int k = 0; k < 128; k++) acc = fmaf(hrow[k], Wc[k * 10 + c], acc);
    const float* prow = perm + g * 64;
#pragma unroll 8
    for (int p = 0; p < 64; p++) acc = fmaf(prow[p], Wc[(128 + p) * 10 + c], acc);
    out[t] = acc;
}

extern "C" void kernel_launch(void* const* d_in, const int* in_sizes, int n_in,
                              void* d_out, int out_size, void* d_ws, size_t ws_size,
                              hipStream_t stream) {
    const float* h    = (const float*)d_in[0];
    const float* perm = (const float*)d_in[1];
    const float* W1   = (const float*)d_in[2];
    const float* b1   = (const float*)d_in[3];
    const float* W2   = (const float*)d_in[4];
    const float* b2   = (const float*)d_in[5];
    const float* Wc   = (const float*)d_in[6];
    const float* bc   = (const float*)d_in[7];
    const int* src    = (const int*)d_in[8];
    const int* dst    = (const int*)d_in[9];
    const int* gids   = (const int*)d_in[10];
    float* out = (float*)d_out;

    const int N = in_sizes[0] / 128;
    const int E = in_sizes[8];
    const int G = NUM_G, H = 128;

    char* w = (char*)d_ws;
    size_t off = 0;
    auto alloc = [&](size_t bytes) -> void* {
        void* p = w + off;
        off = (off + bytes + 255) & ~(size_t)255;
        return p;
    };
    float* bufA     = (float*)alloc((size_t)N * H * 4);   // xs -> agg2 -> x2
    float* bufB     = (float*)alloc((size_t)N * H * 4);   // agg1 -> x1s (in-place gemm)
    int*   bucket   = (int*)alloc((size_t)N * BUCKET_CAP * 4);
    int*   indeg    = (int*)alloc((size_t)N * 4);
    int*   outdeg   = (int*)alloc((size_t)N * 4);
    float* nrm_out  = (float*)alloc((size_t)N * 4);
    float* nrm_in   = (float*)alloc((size_t)N * 4);
    int*   goffs    = (int*)alloc((size_t)(G + 1) * 4);
    float* hg       = (float*)alloc((size_t)G * H * 4);
    int*   ovfc     = (int*)alloc(256);
    int*   ovfl     = (int*)alloc((size_t)OVF_CAP * 4);

    (void)hipMemsetAsync(indeg, 0, (size_t)N * 4, stream);
    (void)hipMemsetAsync(outdeg, 0, (size_t)N * 4, stream);
    (void)hipMemsetAsync(ovfc, 0, 4, stream);

    const int E4 = (E + 3) / 4;
    outdeg_kernel<<<(E4 + 255) / 256, 256, 0, stream>>>(src, E, outdeg);

    const int chunk = (N + NPASS - 1) / NPASS;
    for (int p = 0; p < NPASS; p++) {
        int lo = p * chunk;
        int hi = (lo + chunk < N) ? lo + chunk : N;
        if (lo >= N) break;
        build_pass_kernel<<<(E4 + 255) / 256, 256, 0, stream>>>(
            src, dst, E, lo, hi, indeg, bucket, ovfc, ovfl);
    }

    goffs_kernel<<<(N + 1 + 255) / 256, 256, 0, stream>>>(gids, N, goffs);
    norm_kernel<<<(N + 255) / 256, 256, 0, stream>>>(outdeg, indeg, nrm_out, nrm_in, N);

    // layer 1: xs = h*nrm_out (A); agg -> B; gemm in-place on B with relu*nrm_out
    scale_kernel<<<(N * 32 + 255) / 256, 256, 0, stream>>>(h, nrm_out, bufA, N);
    agg_kernel<<<(N * 32 + 255) / 256, 256, 0, stream>>>(bufA, bucket, indeg, bufB, N);
    ovf_kernel<<<(OVF_CAP * 32) / 256, 256, 0, stream>>>(bufA, src, dst, ovfc, ovfl, bufB);
    gemm128<<<(N + 127) / 128, 256, 0, stream>>>(bufB, W1, b1, nrm_in, nrm_out, bufB, N, 1);

    // layer 2: agg(B) -> A; gemm in-place on A (no relu, no postscale)
    agg_kernel<<<(N * 32 + 255) / 256, 256, 0, stream>>>(bufB, bucket, indeg, bufA, N);
    ovf_kernel<<<(OVF_CAP * 32) / 256, 256, 0, stream>>>(bufB, src, dst, ovfc, ovfl, bufA);
    gemm128<<<(N + 127) / 128, 256, 0, stream>>>(bufA, W2, b2, nrm_in, nullptr, bufA, N, 0);

    // readout
    mean_kernel<<<G, 1024, 0, stream>>>(bufA, goffs, hg);
    final_kernel<<<(G * 10 + 255) / 256, 256, 0, stream>>>(hg, perm, Wc, bc, out, G);
}

// Round 5
// 683.112 us; speedup vs baseline: 1.0468x; 1.0468x over previous
//
#include <hip/hip_runtime.h>

// GCN: 2x GraphConv(norm='both') + per-graph mean + [hg|perm] @ Wc + bc
// N=100000, E=1600000, D=H=128, P=64, C=10, G=128
// R5: bf16 gather features (halve gather bytes), exact CSR adjacency build.

#define NUM_G 128

typedef unsigned int uint32;
typedef unsigned short ushort16;

__device__ __forceinline__ float bflo(uint32 u) { return __uint_as_float(u << 16); }
__device__ __forceinline__ float bfhi(uint32 u) { return __uint_as_float(u & 0xffff0000u); }
__device__ __forceinline__ uint32 f2bf_bits(float f) {  // RNE
    uint32 b = __float_as_uint(f);
    return (b + 0x7fffu + ((b >> 16) & 1u)) >> 16;
}
__device__ __forceinline__ uint32 pack2(float a, float b) {
    return f2bf_bits(a) | (f2bf_bits(b) << 16);
}

// ---- degree histograms: one int4 pass over src+dst ----
__global__ void hist_kernel(const int* __restrict__ src, const int* __restrict__ dst, int E,
                            int* __restrict__ outdeg, int* __restrict__ indeg) {
    int t = blockIdx.x * blockDim.x + threadIdx.x;
    int e0 = t * 4;
    if (e0 + 3 < E) {
        int4 s4 = *(const int4*)(src + e0);
        int4 d4 = *(const int4*)(dst + e0);
        atomicAdd(&outdeg[s4.x], 1); atomicAdd(&outdeg[s4.y], 1);
        atomicAdd(&outdeg[s4.z], 1); atomicAdd(&outdeg[s4.w], 1);
        atomicAdd(&indeg[d4.x], 1); atomicAdd(&indeg[d4.y], 1);
        atomicAdd(&indeg[d4.z], 1); atomicAdd(&indeg[d4.w], 1);
    } else {
        for (int e = e0; e < E; e++) {
            atomicAdd(&outdeg[src[e]], 1);
            atomicAdd(&indeg[dst[e]], 1);
        }
    }
}

// ---- exclusive scan of indeg -> csr offsets (3 small kernels) ----
__global__ void bsum_kernel(const int* __restrict__ indeg, int N, int* __restrict__ bsum) {
    __shared__ int sc[256];
    int i = blockIdx.x * 256 + threadIdx.x;
    sc[threadIdx.x] = (i < N) ? indeg[i] : 0;
    __syncthreads();
    for (int o = 128; o > 0; o >>= 1) {
        if (threadIdx.x < o) sc[threadIdx.x] += sc[threadIdx.x + o];
        __syncthreads();
    }
    if (threadIdx.x == 0) bsum[blockIdx.x] = sc[0];
}

// NB <= 512 (N <= 131072)
__global__ void bscan_kernel(int* __restrict__ bsum, int NB) {
    __shared__ int sc[512];
    int i = threadIdx.x;
    int v = (i < NB) ? bsum[i] : 0;
    sc[i] = v;
    __syncthreads();
    for (int o = 1; o < 512; o <<= 1) {
        int t = (i >= o) ? sc[i - o] : 0;
        __syncthreads();
        sc[i] += t;
        __syncthreads();
    }
    if (i < NB) bsum[i] = sc[i] - v;  // exclusive
}

__global__ void coff_kernel(const int* __restrict__ indeg, const int* __restrict__ bsum,
                            int N, int E, int* __restrict__ coff) {
    __shared__ int sc[256];
    int i = blockIdx.x * 256 + threadIdx.x;
    int v = (i < N) ? indeg[i] : 0;
    sc[threadIdx.x] = v;
    __syncthreads();
    for (int o = 1; o < 256; o <<= 1) {
        int t = (threadIdx.x >= o) ? sc[threadIdx.x - o] : 0;
        __syncthreads();
        sc[threadIdx.x] += t;
        __syncthreads();
    }
    if (i < N) coff[i] = sc[threadIdx.x] - v + bsum[blockIdx.x];
    if (i == N - 1) coff[N] = E;
}

// ---- scatter src ids into exact CSR adjacency (6.4 MB) ----
__global__ void scatter_kernel(const int* __restrict__ src, const int* __restrict__ dst, int E,
                               const int* __restrict__ coff, int* __restrict__ cursor,
                               int* __restrict__ adj) {
    int t = blockIdx.x * blockDim.x + threadIdx.x;
    int e0 = t * 4;
    if (e0 >= E) return;
    int nv = (e0 + 3 < E) ? 4 : (E - e0);
    int s[4], d[4];
    if (nv == 4) {
        int4 s4 = *(const int4*)(src + e0);
        int4 d4 = *(const int4*)(dst + e0);
        s[0] = s4.x; s[1] = s4.y; s[2] = s4.z; s[3] = s4.w;
        d[0] = d4.x; d[1] = d4.y; d[2] = d4.z; d[3] = d4.w;
    } else {
        for (int i = 0; i < nv; i++) { s[i] = src[e0 + i]; d[i] = dst[e0 + i]; }
    }
#pragma unroll
    for (int i = 0; i < 4; i++) {
        if (i >= nv) break;
        int pos = coff[d[i]] + atomicAdd(&cursor[d[i]], 1);
        adj[pos] = s[i];
    }
}

// ---- graph_ids sorted -> segment offsets by boundary detection ----
__global__ void goffs_kernel(const int* __restrict__ gids, int N, int* __restrict__ goffs) {
    int i = blockIdx.x * blockDim.x + threadIdx.x;
    if (i > N) return;
    int prev = (i == 0) ? -1 : gids[i - 1];
    int cur  = (i == N) ? NUM_G : gids[i];
    for (int g = prev + 1; g <= cur && g <= NUM_G; g++) goffs[g] = i;
}

// ---- degree -> rsqrt norms ----
__global__ void norm_kernel(const int* __restrict__ outdeg, const int* __restrict__ indeg,
                            float* __restrict__ nrm_out, float* __restrict__ nrm_in, int N) {
    int i = blockIdx.x * blockDim.x + threadIdx.x;
    if (i >= N) return;
    nrm_out[i] = rsqrtf(fmaxf((float)outdeg[i], 1.0f));
    nrm_in[i]  = rsqrtf(fmaxf((float)indeg[i], 1.0f));
}

// ---- xsb[n] = bf16(h[n] * nrm_out[n]) : 16 lanes/node, 8 elems/lane ----
__global__ void scale_kernel(const float* __restrict__ h, const float* __restrict__ nrm_out,
                             uint32* __restrict__ xsb, int N) {
    int t = blockIdx.x * blockDim.x + threadIdx.x;
    int node = t >> 4, q = t & 15;
    if (node >= N) return;
    float ns = nrm_out[node];
    const float4* hv = (const float4*)(h + (size_t)node * 128 + q * 8);
    float4 a = hv[0], b = hv[1];
    a.x *= ns; a.y *= ns; a.z *= ns; a.w *= ns;
    b.x *= ns; b.y *= ns; b.z *= ns; b.w *= ns;
    uint4 o;
    o.x = pack2(a.x, a.y); o.y = pack2(a.z, a.w);
    o.z = pack2(b.x, b.y); o.w = pack2(b.z, b.w);
    ((uint4*)xsb)[(size_t)node * 16 + q] = o;
}

// ---- aggregation: 16 lanes/node, gather 256 B bf16 rows, fp32 accumulate ----
__global__ void agg_kernel(const uint32* __restrict__ xsb, const int* __restrict__ adj,
                           const int* __restrict__ coff, float* __restrict__ agg, int N) {
    int t = blockIdx.x * blockDim.x + threadIdx.x;
    int node = t >> 4;
    int q = t & 15;
    if (node >= N) return;
    int jb = coff[node], je = coff[node + 1];
    float acc[8];
#pragma unroll
    for (int i = 0; i < 8; i++) acc[i] = 0.f;
    for (int j = jb; j < je; j++) {
        int s = adj[j];
        uint4 u = ((const uint4*)xsb)[(size_t)s * 16 + q];
        acc[0] += bflo(u.x); acc[1] += bfhi(u.x);
        acc[2] += bflo(u.y); acc[3] += bfhi(u.y);
        acc[4] += bflo(u.z); acc[5] += bfhi(u.z);
        acc[6] += bflo(u.w); acc[7] += bfhi(u.w);
    }
    float4* o = (float4*)(agg + (size_t)node * 128 + q * 8);
    o[0] = make_float4(acc[0], acc[1], acc[2], acc[3]);
    o[1] = make_float4(acc[4], acc[5], acc[6], acc[7]);
}

// ---- out[r][c] = act(rowscale[r]*sum_k A[r][k]*W[k][c] + bias[c]) [*post[r]] ----
// W fp32 in LDS. 256 threads: 64 row-pairs x 4 col-groups. In-place-safe (fp32 out).
// OUT_BF16: pack epilogue to bf16 rows (layer-1 output = next gather source).
template <bool OUT_BF16>
__global__ __launch_bounds__(256) void gemm128(const float* A,
                                               const float* __restrict__ W,
                                               const float* __restrict__ bias,
                                               const float* __restrict__ rowscale,
                                               const float* __restrict__ postscale,
                                               void* out, int N, int do_relu) {
    __shared__ float Wl[128 * 128];
    for (int i = threadIdx.x; i < 4096; i += 256)
        ((float4*)Wl)[i] = ((const float4*)W)[i];
    __syncthreads();

    int gi = threadIdx.x & 3;
    int rp = threadIdx.x >> 2;
    int r0 = blockIdx.x * 128 + rp * 2;
    if (r0 >= N) return;
    bool two = (r0 + 1 < N);

    const float* A0 = A + (size_t)r0 * 128;
    const float* A1 = two ? (A0 + 128) : A0;

    float acc0[32], acc1[32];
#pragma unroll
    for (int j = 0; j < 32; j++) { acc0[j] = 0.f; acc1[j] = 0.f; }

    for (int k4 = 0; k4 < 32; k4++) {
        float4 a0 = ((const float4*)A0)[k4];
        float4 a1 = ((const float4*)A1)[k4];
#pragma unroll
        for (int kk = 0; kk < 4; kk++) {
            int k = k4 * 4 + kk;
            float av0 = (kk == 0) ? a0.x : (kk == 1) ? a0.y : (kk == 2) ? a0.z : a0.w;
            float av1 = (kk == 0) ? a1.x : (kk == 1) ? a1.y : (kk == 2) ? a1.z : a1.w;
            const float* wrow = Wl + k * 128 + gi * 4;
#pragma unroll
            for (int m = 0; m < 8; m++) {
                float4 wv = *(const float4*)(wrow + m * 16);
                acc0[m * 4 + 0] = fmaf(av0, wv.x, acc0[m * 4 + 0]);
                acc0[m * 4 + 1] = fmaf(av0, wv.y, acc0[m * 4 + 1]);
                acc0[m * 4 + 2] = fmaf(av0, wv.z, acc0[m * 4 + 2]);
                acc0[m * 4 + 3] = fmaf(av0, wv.w, acc0[m * 4 + 3]);
                acc1[m * 4 + 0] = fmaf(av1, wv.x, acc1[m * 4 + 0]);
                acc1[m * 4 + 1] = fmaf(av1, wv.y, acc1[m * 4 + 1]);
                acc1[m * 4 + 2] = fmaf(av1, wv.z, acc1[m * 4 + 2]);
                acc1[m * 4 + 3] = fmaf(av1, wv.w, acc1[m * 4 + 3]);
            }
        }
    }

    float s0 = rowscale[r0];
    float s1 = two ? rowscale[r0 + 1] : 0.f;
    float p0 = 1.f, p1 = 1.f;
    if (postscale) {
        p0 = postscale[r0];
        p1 = two ? postscale[r0 + 1] : 0.f;
    }
#pragma unroll
    for (int m = 0; m < 8; m++) {
        int c = m * 16 + gi * 4;
        float4 b4 = *(const float4*)(bias + c);
        float4 v0, v1;
        v0.x = fmaf(s0, acc0[m * 4 + 0], b4.x);
        v0.y = fmaf(s0, acc0[m * 4 + 1], b4.y);
        v0.z = fmaf(s0, acc0[m * 4 + 2], b4.z);
        v0.w = fmaf(s0, acc0[m * 4 + 3], b4.w);
        if (do_relu) {
            v0.x = fmaxf(v0.x, 0.f); v0.y = fmaxf(v0.y, 0.f);
            v0.z = fmaxf(v0.z, 0.f); v0.w = fmaxf(v0.w, 0.f);
        }
        v0.x *= p0; v0.y *= p0; v0.z *= p0; v0.w *= p0;
        if (OUT_BF16) {
            uint2 pk; pk.x = pack2(v0.x, v0.y); pk.y = pack2(v0.z, v0.w);
            *(uint2*)((uint32*)out + (size_t)r0 * 64 + (c >> 1)) = pk;
        } else {
            *(float4*)((float*)out + (size_t)r0 * 128 + c) = v0;
        }
        if (two) {
            v1.x = fmaf(s1, acc1[m * 4 + 0], b4.x);
            v1.y = fmaf(s1, acc1[m * 4 + 1], b4.y);
            v1.z = fmaf(s1, acc1[m * 4 + 2], b4.z);
            v1.w = fmaf(s1, acc1[m * 4 + 3], b4.w);
            if (do_relu) {
                v1.x = fmaxf(v1.x, 0.f); v1.y = fmaxf(v1.y, 0.f);
                v1.z = fmaxf(v1.z, 0.f); v1.w = fmaxf(v1.w, 0.f);
            }
            v1.x *= p1; v1.y *= p1; v1.z *= p1; v1.w *= p1;
            if (OUT_BF16) {
                uint2 pk; pk.x = pack2(v1.x, v1.y); pk.y = pack2(v1.z, v1.w);
                *(uint2*)((uint32*)out + (size_t)(r0 + 1) * 64 + (c >> 1)) = pk;
            } else {
                *(float4*)((float*)out + (size_t)(r0 + 1) * 128 + c) = v1;
            }
        }
    }
}

// ---- per-graph mean: block per graph, 8 row-lanes x 128 cols + LDS reduce ----
__global__ __launch_bounds__(1024) void mean_kernel(const float* __restrict__ x2,
                                                    const int* __restrict__ goffs,
                                                    float* __restrict__ hg) {
    __shared__ float red[8][128];
    int g = blockIdx.x;
    int c = threadIdx.x & 127;
    int j = threadIdx.x >> 7;
    int s = goffs[g], e = goffs[g + 1];
    float acc = 0.f;
    for (int r = s + j; r < e; r += 8) acc += x2[(size_t)r * 128 + c];
    red[j][c] = acc;
    __syncthreads();
    if (j == 0) {
        float t = red[0][c];
#pragma unroll
        for (int jj = 1; jj < 8; jj++) t += red[jj][c];
        float cnt = fmaxf((float)(e - s), 1.0f);
        hg[g * 128 + c] = t / cnt;
    }
}

// ---- classifier head: [G,128|64] @ Wc[192,10] + bc ----
__global__ void final_kernel(const float* __restrict__ hg, const float* __restrict__ perm,
                             const float* __restrict__ Wc, const float* __restrict__ bc,
                             float* __restrict__ out, int G) {
    int t = blockIdx.x * blockDim.x + threadIdx.x;
    if (t >= G * 10) return;
    int g = t / 10, c = t % 10;
    float acc = bc[c];
    const float* hrow = hg + g * 128;
#pragma unroll 8
    for (int k = 0; k < 128; k++) acc = fmaf(hrow[k], Wc[k * 10 + c], acc);
    const float* prow = perm + g * 64;
#pragma unroll 8
    for (int p = 0; p < 64; p++) acc = fmaf(prow[p], Wc[(128 + p) * 10 + c], acc);
    out[t] = acc;
}

extern "C" void kernel_launch(void* const* d_in, const int* in_sizes, int n_in,
                              void* d_out, int out_size, void* d_ws, size_t ws_size,
                              hipStream_t stream) {
    const float* h    = (const float*)d_in[0];
    const float* perm = (const float*)d_in[1];
    const float* W1   = (const float*)d_in[2];
    const float* b1   = (const float*)d_in[3];
    const float* W2   = (const float*)d_in[4];
    const float* b2   = (const float*)d_in[5];
    const float* Wc   = (const float*)d_in[6];
    const float* bc   = (const float*)d_in[7];
    const int* src    = (const int*)d_in[8];
    const int* dst    = (const int*)d_in[9];
    const int* gids   = (const int*)d_in[10];
    float* out = (float*)d_out;

    const int N = in_sizes[0] / 128;
    const int E = in_sizes[8];
    const int G = NUM_G, H = 128;

    char* w = (char*)d_ws;
    size_t off = 0;
    auto alloc = [&](size_t bytes) -> void* {
        void* p = w + off;
        off = (off + bytes + 255) & ~(size_t)255;
        return p;
    };
    float*  aggF    = (float*)alloc((size_t)N * H * 4);    // agg out / gemm2 in-place / x2
    uint32* xsb     = (uint32*)alloc((size_t)N * H * 2);   // bf16 scaled input features
    uint32* x1b     = (uint32*)alloc((size_t)N * H * 2);   // bf16 layer-1 output
    int*    adj     = (int*)alloc((size_t)E * 4);          // CSR adjacency
    int*    coff    = (int*)alloc((size_t)(N + 1) * 4);
    int*    indeg   = (int*)alloc((size_t)N * 4);
    int*    outdeg  = (int*)alloc((size_t)N * 4);
    int*    cursor  = (int*)alloc((size_t)N * 4);
    float*  nrm_out = (float*)alloc((size_t)N * 4);
    float*  nrm_in  = (float*)alloc((size_t)N * 4);
    int*    bsum    = (int*)alloc((size_t)512 * 4);
    int*    goffs   = (int*)alloc((size_t)(G + 1) * 4);
    float*  hg      = (float*)alloc((size_t)G * H * 4);

    (void)hipMemsetAsync(indeg, 0, (size_t)N * 4, stream);
    (void)hipMemsetAsync(outdeg, 0, (size_t)N * 4, stream);
    (void)hipMemsetAsync(cursor, 0, (size_t)N * 4, stream);

    const int E4 = (E + 3) / 4;
    const int NB = (N + 255) / 256;

    hist_kernel<<<(E4 + 255) / 256, 256, 0, stream>>>(src, dst, E, outdeg, indeg);
    bsum_kernel<<<NB, 256, 0, stream>>>(indeg, N, bsum);
    bscan_kernel<<<1, 512, 0, stream>>>(bsum, NB);
    coff_kernel<<<NB, 256, 0, stream>>>(indeg, bsum, N, E, coff);
    scatter_kernel<<<(E4 + 255) / 256, 256, 0, stream>>>(src, dst, E, coff, cursor, adj);

    goffs_kernel<<<(N + 1 + 255) / 256, 256, 0, stream>>>(gids, N, goffs);
    norm_kernel<<<(N + 255) / 256, 256, 0, stream>>>(outdeg, indeg, nrm_out, nrm_in, N);

    // layer 1: xsb = bf16(h*nrm_out); agg -> aggF; gemm -> x1b (bf16, relu*nrm_out fused)
    scale_kernel<<<(N * 16 + 255) / 256, 256, 0, stream>>>(h, nrm_out, xsb, N);
    agg_kernel<<<(N * 16 + 255) / 256, 256, 0, stream>>>(xsb, adj, coff, aggF, N);
    gemm128<true><<<(N + 127) / 128, 256, 0, stream>>>(aggF, W1, b1, nrm_in, nrm_out, x1b, N, 1);

    // layer 2: agg(x1b) -> aggF; gemm in-place fp32 (no relu, no postscale)
    agg_kernel<<<(N * 16 + 255) / 256, 256, 0, stream>>>(x1b, adj, coff, aggF, N);
    gemm128<false><<<(N + 127) / 128, 256, 0, stream>>>(aggF, W2, b2, nrm_in, nullptr, aggF, N, 0);

    // readout
    mean_kernel<<<G, 1024, 0, stream>>>(aggF, goffs, hg);
    final_kernel<<<(G * 10 + 255) / 256, 256, 0, stream>>>(hg, perm, Wc, bc, out, G);
}

// Round 6
// 513.076 us; speedup vs baseline: 1.3937x; 1.3314x over previous
//
#include <hip/hip_runtime.h>

// GCN: 2x GraphConv(norm='both') + per-graph mean + [hg|perm] @ Wc + bc
// N=100000, E=1600000, D=H=128, P=64, C=10, G=128
// R6: atomic-free graph build via two-level partition (LDS hists + coalesced
// writes) replacing global-atomic hist/scatter (was ~200us of 32B-RMW traffic).

#define NUM_G 128
#define PB_EDGES 4096   // edges per partition block
#define W_BIN 128       // nodes per bin (key>>7)

typedef unsigned int uint32;

__device__ __forceinline__ float bflo(uint32 u) { return __uint_as_float(u << 16); }
__device__ __forceinline__ float bfhi(uint32 u) { return __uint_as_float(u & 0xffff0000u); }
__device__ __forceinline__ uint32 f2bf_bits(float f) {  // RNE
    uint32 b = __float_as_uint(f);
    return (b + 0x7fffu + ((b >> 16) & 1u)) >> 16;
}
__device__ __forceinline__ uint32 pack2(float a, float b) {
    return f2bf_bits(a) | (f2bf_bits(b) << 16);
}

// ---- P1: per-block LDS histogram of key>>7. pipe0=dst, pipe1=src ----
__global__ __launch_bounds__(256) void p1_hist(const int* __restrict__ src,
                                               const int* __restrict__ dst, int E,
                                               int NBIN, int B, int* __restrict__ bh) {
    __shared__ int hist[1024];
    int b = blockIdx.x;
    int pipe = (b >= B) ? 1 : 0;
    int bb = pipe ? b - B : b;
    const int* key = pipe ? src : dst;
    for (int i = threadIdx.x; i < NBIN; i += 256) hist[i] = 0;
    __syncthreads();
    int base = bb * PB_EDGES;
    for (int c = threadIdx.x; c < PB_EDGES / 4; c += 256) {
        int e = base + c * 4;
        if (e + 3 < E) {
            int4 k4 = *(const int4*)(key + e);
            atomicAdd(&hist[k4.x >> 7], 1);
            atomicAdd(&hist[k4.y >> 7], 1);
            atomicAdd(&hist[k4.z >> 7], 1);
            atomicAdd(&hist[k4.w >> 7], 1);
        } else {
            for (int i = e; i < E && i < e + 4; i++) atomicAdd(&hist[key[i] >> 7], 1);
        }
    }
    __syncthreads();
    int* outp = bh + (size_t)pipe * NBIN * B;
    for (int k = threadIdx.x; k < NBIN; k += 256)
        outp[(size_t)k * B + bb] = hist[k];
}

// ---- P2a: tot[pipe][k] = sum_b bh[pipe][k][b] ----
__global__ __launch_bounds__(256) void p2a_tot(const int* __restrict__ bh, int NBIN, int B,
                                               int* __restrict__ tot) {
    __shared__ int sc[256];
    int k = blockIdx.x % NBIN, pipe = blockIdx.x / NBIN;
    const int* row = bh + (size_t)pipe * NBIN * B + (size_t)k * B;
    int acc = 0;
    for (int b = threadIdx.x; b < B; b += 256) acc += row[b];
    sc[threadIdx.x] = acc;
    __syncthreads();
    for (int o = 128; o > 0; o >>= 1) {
        if (threadIdx.x < o) sc[threadIdx.x] += sc[threadIdx.x + o];
        __syncthreads();
    }
    if (threadIdx.x == 0) tot[pipe * NBIN + k] = sc[0];
}

// ---- P2b: exclusive scan tot -> binStart (NBIN <= 1024) ----
__global__ __launch_bounds__(1024) void p2b_scan(const int* __restrict__ tot, int NBIN, int E,
                                                 int* __restrict__ bstart) {
    __shared__ int sc[1024];
    int pipe = blockIdx.x;
    int i = threadIdx.x;
    int v = (i < NBIN) ? tot[pipe * NBIN + i] : 0;
    sc[i] = v;
    __syncthreads();
    for (int o = 1; o < 1024; o <<= 1) {
        int t = (i >= o) ? sc[i - o] : 0;
        __syncthreads();
        sc[i] += t;
        __syncthreads();
    }
    if (i < NBIN) bstart[pipe * (NBIN + 1) + i] = sc[i] - v;
    if (i == 0) bstart[pipe * (NBIN + 1) + NBIN] = E;
}

// ---- P2c: per-(block,bin) absolute cursors, block-major output (B <= 512) ----
__global__ __launch_bounds__(512) void p2c_cursor(const int* __restrict__ bh,
                                                  const int* __restrict__ bstart,
                                                  int NBIN, int B, int* __restrict__ curs) {
    __shared__ int sc[512];
    int k = blockIdx.x % NBIN, pipe = blockIdx.x / NBIN;
    const int* row = bh + (size_t)pipe * NBIN * B + (size_t)k * B;
    int i = threadIdx.x;
    int v = (i < B) ? row[i] : 0;
    sc[i] = v;
    __syncthreads();
    for (int o = 1; o < 512; o <<= 1) {
        int t = (i >= o) ? sc[i - o] : 0;
        __syncthreads();
        sc[i] += t;
        __syncthreads();
    }
    int base = bstart[pipe * (NBIN + 1) + k];
    if (i < B)
        curs[(size_t)pipe * B * NBIN + (size_t)i * NBIN + k] = base + sc[i] - v;
}

// ---- P3: scatter edges into bin-partitioned buffers (LDS cursors) ----
__global__ __launch_bounds__(256) void p3_scatter(const int* __restrict__ src,
                                                  const int* __restrict__ dst, int E,
                                                  int NBIN, int B, const int* __restrict__ curs,
                                                  int2* __restrict__ ebuf, int* __restrict__ sbuf) {
    __shared__ int cur[1024];
    int b = blockIdx.x;
    int pipe = (b >= B) ? 1 : 0;
    int bb = pipe ? b - B : b;
    const int* crow = curs + (size_t)pipe * B * NBIN + (size_t)bb * NBIN;
    for (int i = threadIdx.x; i < NBIN; i += 256) cur[i] = crow[i];
    __syncthreads();
    int base = bb * PB_EDGES;
    if (!pipe) {
        for (int c = threadIdx.x; c < PB_EDGES / 4; c += 256) {
            int e = base + c * 4;
            if (e + 3 < E) {
                int4 s4 = *(const int4*)(src + e);
                int4 d4 = *(const int4*)(dst + e);
                int p;
                p = atomicAdd(&cur[d4.x >> 7], 1); ebuf[p] = make_int2(s4.x, d4.x);
                p = atomicAdd(&cur[d4.y >> 7], 1); ebuf[p] = make_int2(s4.y, d4.y);
                p = atomicAdd(&cur[d4.z >> 7], 1); ebuf[p] = make_int2(s4.z, d4.z);
                p = atomicAdd(&cur[d4.w >> 7], 1); ebuf[p] = make_int2(s4.w, d4.w);
            } else {
                for (int i = e; i < E && i < e + 4; i++) {
                    int s = src[i], d = dst[i];
                    int p = atomicAdd(&cur[d >> 7], 1);
                    ebuf[p] = make_int2(s, d);
                }
            }
        }
    } else {
        for (int c = threadIdx.x; c < PB_EDGES / 4; c += 256) {
            int e = base + c * 4;
            if (e + 3 < E) {
                int4 s4 = *(const int4*)(src + e);
                int p;
                p = atomicAdd(&cur[s4.x >> 7], 1); sbuf[p] = s4.x;
                p = atomicAdd(&cur[s4.y >> 7], 1); sbuf[p] = s4.y;
                p = atomicAdd(&cur[s4.z >> 7], 1); sbuf[p] = s4.z;
                p = atomicAdd(&cur[s4.w >> 7], 1); sbuf[p] = s4.w;
            } else {
                for (int i = e; i < E && i < e + 4; i++) {
                    int s = src[i];
                    int p = atomicAdd(&cur[s >> 7], 1);
                    sbuf[p] = s;
                }
            }
        }
    }
}

// ---- P4: per-bin fine CSR: LDS hist+scan+scatter, coalesced adj/indeg/coff ----
__global__ __launch_bounds__(256) void p4_csr(const int2* __restrict__ ebuf,
                                              const int* __restrict__ bstart,
                                              int NBIN, int N, int E,
                                              int* __restrict__ indeg, int* __restrict__ coff,
                                              int* __restrict__ adj) {
    __shared__ int hist[128];
    __shared__ int sc[128];
    __shared__ int cur[128];
    __shared__ int lsrc[4096];
    int k = blockIdx.x;
    int tid = threadIdx.x;
    int s0 = bstart[k], s1 = bstart[k + 1];
    int M = s1 - s0;
    if (tid < 128) hist[tid] = 0;
    __syncthreads();
    for (int i = tid; i < M; i += 256) {
        int2 e = ebuf[s0 + i];
        atomicAdd(&hist[e.y & 127], 1);
    }
    __syncthreads();
    if (tid < 128) sc[tid] = hist[tid];
    __syncthreads();
    for (int o = 1; o < 128; o <<= 1) {
        int v = 0;
        if (tid < 128 && tid >= o) v = sc[tid - o];
        __syncthreads();
        if (tid < 128) sc[tid] += v;
        __syncthreads();
    }
    if (tid < 128) {
        int node = k * W_BIN + tid;
        if (node < N) {
            indeg[node] = hist[tid];
            coff[node] = s0 + sc[tid] - hist[tid];  // exclusive
        }
        cur[tid] = sc[tid] - hist[tid];
    }
    if (k == NBIN - 1 && tid == 0) coff[N] = E;
    __syncthreads();
    if (M <= 4096) {
        for (int i = tid; i < M; i += 256) {
            int2 e = ebuf[s0 + i];
            int p = atomicAdd(&cur[e.y & 127], 1);
            lsrc[p] = e.x;
        }
        __syncthreads();
        for (int i = tid; i < M; i += 256) adj[s0 + i] = lsrc[i];
    } else {  // overflow fallback: correct, uncoalesced (never expected)
        for (int i = tid; i < M; i += 256) {
            int2 e = ebuf[s0 + i];
            int p = atomicAdd(&cur[e.y & 127], 1);
            adj[s0 + p] = e.x;
        }
    }
}

// ---- P4s: per-bin outdeg histogram from partitioned src values ----
__global__ __launch_bounds__(256) void p4s_outdeg(const int* __restrict__ sbuf,
                                                  const int* __restrict__ bstartS,
                                                  int N, int* __restrict__ outdeg) {
    __shared__ int hist[128];
    int k = blockIdx.x;
    int tid = threadIdx.x;
    int s0 = bstartS[k], s1 = bstartS[k + 1];
    if (tid < 128) hist[tid] = 0;
    __syncthreads();
    for (int i = s0 + tid; i < s1; i += 256) atomicAdd(&hist[sbuf[i] & 127], 1);
    __syncthreads();
    if (tid < 128) {
        int node = k * W_BIN + tid;
        if (node < N) outdeg[node] = hist[tid];
    }
}

// ---- graph_ids sorted -> segment offsets by boundary detection ----
__global__ void goffs_kernel(const int* __restrict__ gids, int N, int* __restrict__ goffs) {
    int i = blockIdx.x * blockDim.x + threadIdx.x;
    if (i > N) return;
    int prev = (i == 0) ? -1 : gids[i - 1];
    int cur  = (i == N) ? NUM_G : gids[i];
    for (int g = prev + 1; g <= cur && g <= NUM_G; g++) goffs[g] = i;
}

// ---- degree -> rsqrt norms ----
__global__ void norm_kernel(const int* __restrict__ outdeg, const int* __restrict__ indeg,
                            float* __restrict__ nrm_out, float* __restrict__ nrm_in, int N) {
    int i = blockIdx.x * blockDim.x + threadIdx.x;
    if (i >= N) return;
    nrm_out[i] = rsqrtf(fmaxf((float)outdeg[i], 1.0f));
    nrm_in[i]  = rsqrtf(fmaxf((float)indeg[i], 1.0f));
}

// ---- xsb[n] = bf16(h[n] * nrm_out[n]) : 16 lanes/node, 8 elems/lane ----
__global__ void scale_kernel(const float* __restrict__ h, const float* __restrict__ nrm_out,
                             uint32* __restrict__ xsb, int N) {
    int t = blockIdx.x * blockDim.x + threadIdx.x;
    int node = t >> 4, q = t & 15;
    if (node >= N) return;
    float ns = nrm_out[node];
    const float4* hv = (const float4*)(h + (size_t)node * 128 + q * 8);
    float4 a = hv[0], b = hv[1];
    a.x *= ns; a.y *= ns; a.z *= ns; a.w *= ns;
    b.x *= ns; b.y *= ns; b.z *= ns; b.w *= ns;
    uint4 o;
    o.x = pack2(a.x, a.y); o.y = pack2(a.z, a.w);
    o.z = pack2(b.x, b.y); o.w = pack2(b.z, b.w);
    ((uint4*)xsb)[(size_t)node * 16 + q] = o;
}

// ---- aggregation: 16 lanes/node, gather 256 B bf16 rows, fp32 accumulate ----
__global__ void agg_kernel(const uint32* __restrict__ xsb, const int* __restrict__ adj,
                           const int* __restrict__ coff, float* __restrict__ agg, int N) {
    int t = blockIdx.x * blockDim.x + threadIdx.x;
    int node = t >> 4;
    int q = t & 15;
    if (node >= N) return;
    int jb = coff[node], je = coff[node + 1];
    float acc[8];
#pragma unroll
    for (int i = 0; i < 8; i++) acc[i] = 0.f;
    for (int j = jb; j < je; j++) {
        int s = adj[j];
        uint4 u = ((const uint4*)xsb)[(size_t)s * 16 + q];
        acc[0] += bflo(u.x); acc[1] += bfhi(u.x);
        acc[2] += bflo(u.y); acc[3] += bfhi(u.y);
        acc[4] += bflo(u.z); acc[5] += bfhi(u.z);
        acc[6] += bflo(u.w); acc[7] += bfhi(u.w);
    }
    float4* o = (float4*)(agg + (size_t)node * 128 + q * 8);
    o[0] = make_float4(acc[0], acc[1], acc[2], acc[3]);
    o[1] = make_float4(acc[4], acc[5], acc[6], acc[7]);
}

// ---- out[r][c] = act(rowscale[r]*sum_k A[r][k]*W[k][c] + bias[c]) [*post[r]] ----
template <bool OUT_BF16>
__global__ __launch_bounds__(256) void gemm128(const float* A,
                                               const float* __restrict__ W,
                                               const float* __restrict__ bias,
                                               const float* __restrict__ rowscale,
                                               const float* __restrict__ postscale,
                                               void* out, int N, int do_relu) {
    __shared__ float Wl[128 * 128];
    for (int i = threadIdx.x; i < 4096; i += 256)
        ((float4*)Wl)[i] = ((const float4*)W)[i];
    __syncthreads();

    int gi = threadIdx.x & 3;
    int rp = threadIdx.x >> 2;
    int r0 = blockIdx.x * 128 + rp * 2;
    if (r0 >= N) return;
    bool two = (r0 + 1 < N);

    const float* A0 = A + (size_t)r0 * 128;
    const float* A1 = two ? (A0 + 128) : A0;

    float acc0[32], acc1[32];
#pragma unroll
    for (int j = 0; j < 32; j++) { acc0[j] = 0.f; acc1[j] = 0.f; }

    for (int k4 = 0; k4 < 32; k4++) {
        float4 a0 = ((const float4*)A0)[k4];
        float4 a1 = ((const float4*)A1)[k4];
#pragma unroll
        for (int kk = 0; kk < 4; kk++) {
            int k = k4 * 4 + kk;
            float av0 = (kk == 0) ? a0.x : (kk == 1) ? a0.y : (kk == 2) ? a0.z : a0.w;
            float av1 = (kk == 0) ? a1.x : (kk == 1) ? a1.y : (kk == 2) ? a1.z : a1.w;
            const float* wrow = Wl + k * 128 + gi * 4;
#pragma unroll
            for (int m = 0; m < 8; m++) {
                float4 wv = *(const float4*)(wrow + m * 16);
                acc0[m * 4 + 0] = fmaf(av0, wv.x, acc0[m * 4 + 0]);
                acc0[m * 4 + 1] = fmaf(av0, wv.y, acc0[m * 4 + 1]);
                acc0[m * 4 + 2] = fmaf(av0, wv.z, acc0[m * 4 + 2]);
                acc0[m * 4 + 3] = fmaf(av0, wv.w, acc0[m * 4 + 3]);
                acc1[m * 4 + 0] = fmaf(av1, wv.x, acc1[m * 4 + 0]);
                acc1[m * 4 + 1] = fmaf(av1, wv.y, acc1[m * 4 + 1]);
                acc1[m * 4 + 2] = fmaf(av1, wv.z, acc1[m * 4 + 2]);
                acc1[m * 4 + 3] = fmaf(av1, wv.w, acc1[m * 4 + 3]);
            }
        }
    }

    float s0 = rowscale[r0];
    float s1 = two ? rowscale[r0 + 1] : 0.f;
    float p0 = 1.f, p1 = 1.f;
    if (postscale) {
        p0 = postscale[r0];
        p1 = two ? postscale[r0 + 1] : 0.f;
    }
#pragma unroll
    for (int m = 0; m < 8; m++) {
        int c = m * 16 + gi * 4;
        float4 b4 = *(const float4*)(bias + c);
        float4 v0, v1;
        v0.x = fmaf(s0, acc0[m * 4 + 0], b4.x);
        v0.y = fmaf(s0, acc0[m * 4 + 1], b4.y);
        v0.z = fmaf(s0, acc0[m * 4 + 2], b4.z);
        v0.w = fmaf(s0, acc0[m * 4 + 3], b4.w);
        if (do_relu) {
            v0.x = fmaxf(v0.x, 0.f); v0.y = fmaxf(v0.y, 0.f);
            v0.z = fmaxf(v0.z, 0.f); v0.w = fmaxf(v0.w, 0.f);
        }
        v0.x *= p0; v0.y *= p0; v0.z *= p0; v0.w *= p0;
        if (OUT_BF16) {
            uint2 pk; pk.x = pack2(v0.x, v0.y); pk.y = pack2(v0.z, v0.w);
            *(uint2*)((uint32*)out + (size_t)r0 * 64 + (c >> 1)) = pk;
        } else {
            *(float4*)((float*)out + (size_t)r0 * 128 + c) = v0;
        }
        if (two) {
            v1.x = fmaf(s1, acc1[m * 4 + 0], b4.x);
            v1.y = fmaf(s1, acc1[m * 4 + 1], b4.y);
            v1.z = fmaf(s1, acc1[m * 4 + 2], b4.z);
            v1.w = fmaf(s1, acc1[m * 4 + 3], b4.w);
            if (do_relu) {
                v1.x = fmaxf(v1.x, 0.f); v1.y = fmaxf(v1.y, 0.f);
                v1.z = fmaxf(v1.z, 0.f); v1.w = fmaxf(v1.w, 0.f);
            }
            v1.x *= p1; v1.y *= p1; v1.z *= p1; v1.w *= p1;
            if (OUT_BF16) {
                uint2 pk; pk.x = pack2(v1.x, v1.y); pk.y = pack2(v1.z, v1.w);
                *(uint2*)((uint32*)out + (size_t)(r0 + 1) * 64 + (c >> 1)) = pk;
            } else {
                *(float4*)((float*)out + (size_t)(r0 + 1) * 128 + c) = v1;
            }
        }
    }
}

// ---- per-graph mean: block per graph, 8 row-lanes x 128 cols + LDS reduce ----
__global__ __launch_bounds__(1024) void mean_kernel(const float* __restrict__ x2,
                                                    const int* __restrict__ goffs,
                                                    float* __restrict__ hg) {
    __shared__ float red[8][128];
    int g = blockIdx.x;
    int c = threadIdx.x & 127;
    int j = threadIdx.x >> 7;
    int s = goffs[g], e = goffs[g + 1];
    float acc = 0.f;
    for (int r = s + j; r < e; r += 8) acc += x2[(size_t)r * 128 + c];
    red[j][c] = acc;
    __syncthreads();
    if (j == 0) {
        float t = red[0][c];
#pragma unroll
        for (int jj = 1; jj < 8; jj++) t += red[jj][c];
        float cnt = fmaxf((float)(e - s), 1.0f);
        hg[g * 128 + c] = t / cnt;
    }
}

// ---- classifier head: [G,128|64] @ Wc[192,10] + bc ----
__global__ void final_kernel(const float* __restrict__ hg, const float* __restrict__ perm,
                             const float* __restrict__ Wc, const float* __restrict__ bc,
                             float* __restrict__ out, int G) {
    int t = blockIdx.x * blockDim.x + threadIdx.x;
    if (t >= G * 10) return;
    int g = t / 10, c = t % 10;
    float acc = bc[c];
    const float* hrow = hg + g * 128;
#pragma unroll 8
    for (int k = 0; k < 128; k++) acc = fmaf(hrow[k], Wc[k * 10 + c], acc);
    const float* prow = perm + g * 64;
#pragma unroll 8
    for (int p = 0; p < 64; p++) acc = fmaf(prow[p], Wc[(128 + p) * 10 + c], acc);
    out[t] = acc;
}

extern "C" void kernel_launch(void* const* d_in, const int* in_sizes, int n_in,
                              void* d_out, int out_size, void* d_ws, size_t ws_size,
                              hipStream_t stream) {
    const float* h    = (const float*)d_in[0];
    const float* perm = (const float*)d_in[1];
    const float* W1   = (const float*)d_in[2];
    const float* b1   = (const float*)d_in[3];
    const float* W2   = (const float*)d_in[4];
    const float* b2   = (const float*)d_in[5];
    const float* Wc   = (const float*)d_in[6];
    const float* bc   = (const float*)d_in[7];
    const int* src    = (const int*)d_in[8];
    const int* dst    = (const int*)d_in[9];
    const int* gids   = (const int*)d_in[10];
    float* out = (float*)d_out;

    const int N = in_sizes[0] / 128;
    const int E = in_sizes[8];
    const int G = NUM_G, H = 128;
    const int B = (E + PB_EDGES - 1) / PB_EDGES;      // partition blocks (<=512)
    const int NBIN = (N + W_BIN - 1) / W_BIN;         // bins (<=1024)

    char* w = (char*)d_ws;
    size_t off = 0;
    auto alloc = [&](size_t bytes) -> void* {
        void* p = w + off;
        off = (off + bytes + 255) & ~(size_t)255;
        return p;
    };
    float*  aggF    = (float*)alloc((size_t)N * H * 4);    // agg out / gemm in-place / x2
    uint32* xsb     = (uint32*)alloc((size_t)N * H * 2);   // bf16 scaled input features
    uint32* x1b     = (uint32*)alloc((size_t)N * H * 2);   // bf16 layer-1 output
    int*    adj     = (int*)alloc((size_t)E * 4);          // CSR adjacency
    int*    coff    = (int*)alloc((size_t)(N + 1) * 4);
    int*    indeg   = (int*)alloc((size_t)N * 4);
    int*    outdeg  = (int*)alloc((size_t)N * 4);
    float*  nrm_out = (float*)alloc((size_t)N * 4);
    float*  nrm_in  = (float*)alloc((size_t)N * 4);
    int*    goffs   = (int*)alloc((size_t)(G + 1) * 4);
    float*  hg      = (float*)alloc((size_t)G * H * 4);

    // Build temporaries alias aggF (dead until agg_kernel writes it).
    char* tmp = (char*)aggF;
    size_t toff = 0;
    auto talloc = [&](size_t bytes) -> void* {
        void* p = tmp + toff;
        toff = (toff + bytes + 255) & ~(size_t)255;
        return p;
    };
    int2* ebuf   = (int2*)talloc((size_t)E * 8);                 // 12.8 MB
    int*  sbuf   = (int*)talloc((size_t)E * 4);                  // 6.4 MB
    int*  bh     = (int*)talloc((size_t)2 * B * NBIN * 4);       // ~2.5 MB
    int*  curs   = (int*)talloc((size_t)2 * B * NBIN * 4);       // ~2.5 MB
    int*  tot    = (int*)talloc((size_t)2 * NBIN * 4);
    int*  bstart = (int*)talloc((size_t)2 * (NBIN + 1) * 4);

    // ---- atomic-free graph build ----
    p1_hist<<<2 * B, 256, 0, stream>>>(src, dst, E, NBIN, B, bh);
    p2a_tot<<<2 * NBIN, 256, 0, stream>>>(bh, NBIN, B, tot);
    p2b_scan<<<2, 1024, 0, stream>>>(tot, NBIN, E, bstart);
    p2c_cursor<<<2 * NBIN, 512, 0, stream>>>(bh, bstart, NBIN, B, curs);
    p3_scatter<<<2 * B, 256, 0, stream>>>(src, dst, E, NBIN, B, curs, ebuf, sbuf);
    p4_csr<<<NBIN, 256, 0, stream>>>(ebuf, bstart, NBIN, N, E, indeg, coff, adj);
    p4s_outdeg<<<NBIN, 256, 0, stream>>>(sbuf, bstart + (NBIN + 1), N, outdeg);

    goffs_kernel<<<(N + 1 + 255) / 256, 256, 0, stream>>>(gids, N, goffs);
    norm_kernel<<<(N + 255) / 256, 256, 0, stream>>>(outdeg, indeg, nrm_out, nrm_in, N);

    // layer 1: xsb = bf16(h*nrm_out); agg -> aggF; gemm -> x1b (bf16, relu*nrm_out fused)
    scale_kernel<<<(N * 16 + 255) / 256, 256, 0, stream>>>(h, nrm_out, xsb, N);
    agg_kernel<<<(N * 16 + 255) / 256, 256, 0, stream>>>(xsb, adj, coff, aggF, N);
    gemm128<true><<<(N + 127) / 128, 256, 0, stream>>>(aggF, W1, b1, nrm_in, nrm_out, x1b, N, 1);

    // layer 2: agg(x1b) -> aggF; gemm in-place fp32 (no relu, no postscale)
    agg_kernel<<<(N * 16 + 255) / 256, 256, 0, stream>>>(x1b, adj, coff, aggF, N);
    gemm128<false><<<(N + 127) / 128, 256, 0, stream>>>(aggF, W2, b2, nrm_in, nullptr, aggF, N, 0);

    // readout
    mean_kernel<<<G, 1024, 0, stream>>>(aggF, goffs, hg);
    final_kernel<<<(G * 10 + 255) / 256, 256, 0, stream>>>(hg, perm, Wc, bc, out, G);
}

// Round 7
// 396.695 us; speedup vs baseline: 1.8025x; 1.2934x over previous
//
#include <hip/hip_runtime.h>

// GCN: 2x GraphConv(norm='both') + per-graph mean + [hg|perm] @ Wc + bc
// N=100000, E=1600000, D=H=128, P=64, C=10, G=128
// R7: bf16 MFMA GEMM (v_mfma_f32_16x16x32_bf16) replacing fp32 vector GEMM;
// bf16 everywhere between kernels (fp32 accumulate), atomic-free build kept.

#define NUM_G 128
#define PB_EDGES 4096   // edges per partition block
#define W_BIN 128       // nodes per bin (key>>7)

typedef unsigned int uint32;
typedef short bf16x8 __attribute__((ext_vector_type(8)));   // 8 bf16 (4 VGPRs)
typedef float f32x4 __attribute__((ext_vector_type(4)));    // 4 fp32 acc

__device__ __forceinline__ float bflo(uint32 u) { return __uint_as_float(u << 16); }
__device__ __forceinline__ float bfhi(uint32 u) { return __uint_as_float(u & 0xffff0000u); }
__device__ __forceinline__ uint32 f2bf_bits(float f) {  // RNE
    uint32 b = __float_as_uint(f);
    return (b + 0x7fffu + ((b >> 16) & 1u)) >> 16;
}
__device__ __forceinline__ uint32 pack2(float a, float b) {
    return f2bf_bits(a) | (f2bf_bits(b) << 16);
}

// ---- P1: per-block LDS histogram of key>>7. pipe0=dst, pipe1=src ----
__global__ __launch_bounds__(256) void p1_hist(const int* __restrict__ src,
                                               const int* __restrict__ dst, int E,
                                               int NBIN, int B, int* __restrict__ bh) {
    __shared__ int hist[1024];
    int b = blockIdx.x;
    int pipe = (b >= B) ? 1 : 0;
    int bb = pipe ? b - B : b;
    const int* key = pipe ? src : dst;
    for (int i = threadIdx.x; i < NBIN; i += 256) hist[i] = 0;
    __syncthreads();
    int base = bb * PB_EDGES;
    for (int c = threadIdx.x; c < PB_EDGES / 4; c += 256) {
        int e = base + c * 4;
        if (e + 3 < E) {
            int4 k4 = *(const int4*)(key + e);
            atomicAdd(&hist[k4.x >> 7], 1);
            atomicAdd(&hist[k4.y >> 7], 1);
            atomicAdd(&hist[k4.z >> 7], 1);
            atomicAdd(&hist[k4.w >> 7], 1);
        } else {
            for (int i = e; i < E && i < e + 4; i++) atomicAdd(&hist[key[i] >> 7], 1);
        }
    }
    __syncthreads();
    int* outp = bh + (size_t)pipe * NBIN * B;
    for (int k = threadIdx.x; k < NBIN; k += 256)
        outp[(size_t)k * B + bb] = hist[k];
}

// ---- P2a: tot[pipe][k] = sum_b bh[pipe][k][b] ----
__global__ __launch_bounds__(256) void p2a_tot(const int* __restrict__ bh, int NBIN, int B,
                                               int* __restrict__ tot) {
    __shared__ int sc[256];
    int k = blockIdx.x % NBIN, pipe = blockIdx.x / NBIN;
    const int* row = bh + (size_t)pipe * NBIN * B + (size_t)k * B;
    int acc = 0;
    for (int b = threadIdx.x; b < B; b += 256) acc += row[b];
    sc[threadIdx.x] = acc;
    __syncthreads();
    for (int o = 128; o > 0; o >>= 1) {
        if (threadIdx.x < o) sc[threadIdx.x] += sc[threadIdx.x + o];
        __syncthreads();
    }
    if (threadIdx.x == 0) tot[pipe * NBIN + k] = sc[0];
}

// ---- P2b: exclusive scan tot -> binStart (NBIN <= 1024) ----
__global__ __launch_bounds__(1024) void p2b_scan(const int* __restrict__ tot, int NBIN, int E,
                                                 int* __restrict__ bstart) {
    __shared__ int sc[1024];
    int pipe = blockIdx.x;
    int i = threadIdx.x;
    int v = (i < NBIN) ? tot[pipe * NBIN + i] : 0;
    sc[i] = v;
    __syncthreads();
    for (int o = 1; o < 1024; o <<= 1) {
        int t = (i >= o) ? sc[i - o] : 0;
        __syncthreads();
        sc[i] += t;
        __syncthreads();
    }
    if (i < NBIN) bstart[pipe * (NBIN + 1) + i] = sc[i] - v;
    if (i == 0) bstart[pipe * (NBIN + 1) + NBIN] = E;
}

// ---- P2c: per-(block,bin) absolute cursors, block-major output (B <= 512) ----
__global__ __launch_bounds__(512) void p2c_cursor(const int* __restrict__ bh,
                                                  const int* __restrict__ bstart,
                                                  int NBIN, int B, int* __restrict__ curs) {
    __shared__ int sc[512];
    int k = blockIdx.x % NBIN, pipe = blockIdx.x / NBIN;
    const int* row = bh + (size_t)pipe * NBIN * B + (size_t)k * B;
    int i = threadIdx.x;
    int v = (i < B) ? row[i] : 0;
    sc[i] = v;
    __syncthreads();
    for (int o = 1; o < 512; o <<= 1) {
        int t = (i >= o) ? sc[i - o] : 0;
        __syncthreads();
        sc[i] += t;
        __syncthreads();
    }
    int base = bstart[pipe * (NBIN + 1) + k];
    if (i < B)
        curs[(size_t)pipe * B * NBIN + (size_t)i * NBIN + k] = base + sc[i] - v;
}

// ---- P3: scatter edges into bin-partitioned buffers (LDS cursors) ----
__global__ __launch_bounds__(256) void p3_scatter(const int* __restrict__ src,
                                                  const int* __restrict__ dst, int E,
                                                  int NBIN, int B, const int* __restrict__ curs,
                                                  int2* __restrict__ ebuf, int* __restrict__ sbuf) {
    __shared__ int cur[1024];
    int b = blockIdx.x;
    int pipe = (b >= B) ? 1 : 0;
    int bb = pipe ? b - B : b;
    const int* crow = curs + (size_t)pipe * B * NBIN + (size_t)bb * NBIN;
    for (int i = threadIdx.x; i < NBIN; i += 256) cur[i] = crow[i];
    __syncthreads();
    int base = bb * PB_EDGES;
    if (!pipe) {
        for (int c = threadIdx.x; c < PB_EDGES / 4; c += 256) {
            int e = base + c * 4;
            if (e + 3 < E) {
                int4 s4 = *(const int4*)(src + e);
                int4 d4 = *(const int4*)(dst + e);
                int p;
                p = atomicAdd(&cur[d4.x >> 7], 1); ebuf[p] = make_int2(s4.x, d4.x);
                p = atomicAdd(&cur[d4.y >> 7], 1); ebuf[p] = make_int2(s4.y, d4.y);
                p = atomicAdd(&cur[d4.z >> 7], 1); ebuf[p] = make_int2(s4.z, d4.z);
                p = atomicAdd(&cur[d4.w >> 7], 1); ebuf[p] = make_int2(s4.w, d4.w);
            } else {
                for (int i = e; i < E && i < e + 4; i++) {
                    int s = src[i], d = dst[i];
                    int p = atomicAdd(&cur[d >> 7], 1);
                    ebuf[p] = make_int2(s, d);
                }
            }
        }
    } else {
        for (int c = threadIdx.x; c < PB_EDGES / 4; c += 256) {
            int e = base + c * 4;
            if (e + 3 < E) {
                int4 s4 = *(const int4*)(src + e);
                int p;
                p = atomicAdd(&cur[s4.x >> 7], 1); sbuf[p] = s4.x;
                p = atomicAdd(&cur[s4.y >> 7], 1); sbuf[p] = s4.y;
                p = atomicAdd(&cur[s4.z >> 7], 1); sbuf[p] = s4.z;
                p = atomicAdd(&cur[s4.w >> 7], 1); sbuf[p] = s4.w;
            } else {
                for (int i = e; i < E && i < e + 4; i++) {
                    int s = src[i];
                    int p = atomicAdd(&cur[s >> 7], 1);
                    sbuf[p] = s;
                }
            }
        }
    }
}

// ---- P4: per-bin fine CSR: LDS hist+scan+scatter, coalesced adj/indeg/coff ----
__global__ __launch_bounds__(256) void p4_csr(const int2* __restrict__ ebuf,
                                              const int* __restrict__ bstart,
                                              int NBIN, int N, int E,
                                              int* __restrict__ indeg, int* __restrict__ coff,
                                              int* __restrict__ adj) {
    __shared__ int hist[128];
    __shared__ int sc[128];
    __shared__ int cur[128];
    __shared__ int lsrc[4096];
    int k = blockIdx.x;
    int tid = threadIdx.x;
    int s0 = bstart[k], s1 = bstart[k + 1];
    int M = s1 - s0;
    if (tid < 128) hist[tid] = 0;
    __syncthreads();
    for (int i = tid; i < M; i += 256) {
        int2 e = ebuf[s0 + i];
        atomicAdd(&hist[e.y & 127], 1);
    }
    __syncthreads();
    if (tid < 128) sc[tid] = hist[tid];
    __syncthreads();
    for (int o = 1; o < 128; o <<= 1) {
        int v = 0;
        if (tid < 128 && tid >= o) v = sc[tid - o];
        __syncthreads();
        if (tid < 128) sc[tid] += v;
        __syncthreads();
    }
    if (tid < 128) {
        int node = k * W_BIN + tid;
        if (node < N) {
            indeg[node] = hist[tid];
            coff[node] = s0 + sc[tid] - hist[tid];  // exclusive
        }
        cur[tid] = sc[tid] - hist[tid];
    }
    if (k == NBIN - 1 && tid == 0) coff[N] = E;
    __syncthreads();
    if (M <= 4096) {
        for (int i = tid; i < M; i += 256) {
            int2 e = ebuf[s0 + i];
            int p = atomicAdd(&cur[e.y & 127], 1);
            lsrc[p] = e.x;
        }
        __syncthreads();
        for (int i = tid; i < M; i += 256) adj[s0 + i] = lsrc[i];
    } else {  // overflow fallback: correct, uncoalesced (never expected)
        for (int i = tid; i < M; i += 256) {
            int2 e = ebuf[s0 + i];
            int p = atomicAdd(&cur[e.y & 127], 1);
            adj[s0 + p] = e.x;
        }
    }
}

// ---- P4s: per-bin outdeg histogram from partitioned src values ----
__global__ __launch_bounds__(256) void p4s_outdeg(const int* __restrict__ sbuf,
                                                  const int* __restrict__ bstartS,
                                                  int N, int* __restrict__ outdeg) {
    __shared__ int hist[128];
    int k = blockIdx.x;
    int tid = threadIdx.x;
    int s0 = bstartS[k], s1 = bstartS[k + 1];
    if (tid < 128) hist[tid] = 0;
    __syncthreads();
    for (int i = s0 + tid; i < s1; i += 256) atomicAdd(&hist[sbuf[i] & 127], 1);
    __syncthreads();
    if (tid < 128) {
        int node = k * W_BIN + tid;
        if (node < N) outdeg[node] = hist[tid];
    }
}

// ---- graph_ids sorted -> segment offsets by boundary detection ----
__global__ void goffs_kernel(const int* __restrict__ gids, int N, int* __restrict__ goffs) {
    int i = blockIdx.x * blockDim.x + threadIdx.x;
    if (i > N) return;
    int prev = (i == 0) ? -1 : gids[i - 1];
    int cur  = (i == N) ? NUM_G : gids[i];
    for (int g = prev + 1; g <= cur && g <= NUM_G; g++) goffs[g] = i;
}

// ---- degree -> rsqrt norms ----
__global__ void norm_kernel(const int* __restrict__ outdeg, const int* __restrict__ indeg,
                            float* __restrict__ nrm_out, float* __restrict__ nrm_in, int N) {
    int i = blockIdx.x * blockDim.x + threadIdx.x;
    if (i >= N) return;
    nrm_out[i] = rsqrtf(fmaxf((float)outdeg[i], 1.0f));
    nrm_in[i]  = rsqrtf(fmaxf((float)indeg[i], 1.0f));
}

// ---- Wt[n][k] = bf16(W[k][n]) for both layer weights (32 KB each) ----
__global__ void wt_prep(const float* __restrict__ W1, const float* __restrict__ W2,
                        unsigned short* __restrict__ Wt1, unsigned short* __restrict__ Wt2) {
    int tid = blockIdx.x * blockDim.x + threadIdx.x;  // 0..32767
    int sel = tid >> 14;
    int idx = tid & 16383;
    int k = idx >> 7, n = idx & 127;
    float v = (sel ? W2 : W1)[idx];
    unsigned short* o = sel ? Wt2 : Wt1;
    o[n * 128 + k] = (unsigned short)f2bf_bits(v);
}

// ---- xsb[n] = bf16(h[n] * nrm_out[n]) : 16 lanes/node, 8 elems/lane ----
__global__ void scale_kernel(const float* __restrict__ h, const float* __restrict__ nrm_out,
                             uint32* __restrict__ xsb, int N) {
    int t = blockIdx.x * blockDim.x + threadIdx.x;
    int node = t >> 4, q = t & 15;
    if (node >= N) return;
    float ns = nrm_out[node];
    const float4* hv = (const float4*)(h + (size_t)node * 128 + q * 8);
    float4 a = hv[0], b = hv[1];
    a.x *= ns; a.y *= ns; a.z *= ns; a.w *= ns;
    b.x *= ns; b.y *= ns; b.z *= ns; b.w *= ns;
    uint4 o;
    o.x = pack2(a.x, a.y); o.y = pack2(a.z, a.w);
    o.z = pack2(b.x, b.y); o.w = pack2(b.z, b.w);
    ((uint4*)xsb)[(size_t)node * 16 + q] = o;
}

// ---- aggregation: 16 lanes/node, gather 256 B bf16 rows, fp32 acc, bf16 out ----
__global__ void agg_kernel(const uint32* __restrict__ xsb, const int* __restrict__ adj,
                           const int* __restrict__ coff, uint32* __restrict__ aggb, int N) {
    int t = blockIdx.x * blockDim.x + threadIdx.x;
    int node = t >> 4;
    int q = t & 15;
    if (node >= N) return;
    int jb = coff[node], je = coff[node + 1];
    float acc[8];
#pragma unroll
    for (int i = 0; i < 8; i++) acc[i] = 0.f;
    for (int j = jb; j < je; j++) {
        int s = adj[j];
        uint4 u = ((const uint4*)xsb)[(size_t)s * 16 + q];
        acc[0] += bflo(u.x); acc[1] += bfhi(u.x);
        acc[2] += bflo(u.y); acc[3] += bfhi(u.y);
        acc[4] += bflo(u.z); acc[5] += bfhi(u.z);
        acc[6] += bflo(u.w); acc[7] += bfhi(u.w);
    }
    uint4 o;
    o.x = pack2(acc[0], acc[1]); o.y = pack2(acc[2], acc[3]);
    o.z = pack2(acc[4], acc[5]); o.w = pack2(acc[6], acc[7]);
    ((uint4*)aggb)[(size_t)node * 16 + q] = o;
}

// ---- MFMA GEMM: out[r][c] = act(rowscale[r]*sum_k A[r][k]*W[k][c]+bias[c])*post[r] ----
// A [N,128] bf16; Wt [n][k] bf16 staged in LDS (pitch 136: conflict-free b128).
// 4 waves x 16 rows = 64 rows/block; per wave: 4 k-steps x 8 n-tiles MFMA.
// Frag maps (verified m89/m91/m120): A[m=lane&15][k=quad*8+j];
// B[k=quad*8+j][n=lane&15]; C col=lane&15, row=quad*4+reg.
__global__ __launch_bounds__(256) void gemm_mfma(const unsigned short* __restrict__ A,
                                                 const unsigned short* __restrict__ Wtg,
                                                 const float* __restrict__ bias,
                                                 const float* __restrict__ rowscale,
                                                 const float* __restrict__ postscale,
                                                 unsigned short* __restrict__ out,
                                                 int N, int do_relu) {
    __shared__ unsigned short Wl[128 * 136];
    for (int i = threadIdx.x; i < 2048; i += 256) {
        uint4 v = ((const uint4*)Wtg)[i];
        *(uint4*)&Wl[(i >> 4) * 136 + (i & 15) * 8] = v;
    }
    __syncthreads();

    int lane = threadIdx.x & 63;
    int wv = threadIdx.x >> 6;
    int col_l = lane & 15;
    int quad = lane >> 4;
    int r0w = blockIdx.x * 64 + wv * 16;
    if (r0w >= N) return;

    int arow = r0w + col_l;
    if (arow >= N) arow = N - 1;
    const unsigned short* Arow = A + (size_t)arow * 128;

    f32x4 acc[8];
#pragma unroll
    for (int t = 0; t < 8; t++) { acc[t][0] = 0.f; acc[t][1] = 0.f; acc[t][2] = 0.f; acc[t][3] = 0.f; }

#pragma unroll
    for (int kk = 0; kk < 4; kk++) {
        bf16x8 a = *(const bf16x8*)(Arow + kk * 32 + quad * 8);
        const unsigned short* wb = &Wl[(size_t)col_l * 136 + kk * 32 + quad * 8];
#pragma unroll
        for (int t = 0; t < 8; t++) {
            bf16x8 b = *(const bf16x8*)(wb + (size_t)t * 16 * 136);
            acc[t] = __builtin_amdgcn_mfma_f32_16x16x32_bf16(a, b, acc[t], 0, 0, 0);
        }
    }

    float s[4], p[4];
#pragma unroll
    for (int j = 0; j < 4; j++) {
        int rw = r0w + quad * 4 + j;
        bool ok = rw < N;
        s[j] = ok ? rowscale[rw] : 0.f;
        p[j] = (postscale != nullptr && ok) ? postscale[rw] : 1.f;
    }
#pragma unroll
    for (int t = 0; t < 8; t++) {
        int c = t * 16 + col_l;
        float bia = bias[c];
#pragma unroll
        for (int j = 0; j < 4; j++) {
            int rw = r0w + quad * 4 + j;
            if (rw >= N) continue;
            float v = fmaf(s[j], acc[t][j], bia);
            if (do_relu) v = fmaxf(v, 0.f);
            v *= p[j];
            out[(size_t)rw * 128 + c] = (unsigned short)f2bf_bits(v);
        }
    }
}

// ---- per-graph mean over bf16 rows: 16 row-lanes x 64 col-pairs + LDS reduce ----
__global__ __launch_bounds__(1024) void mean_kernel(const uint32* __restrict__ x2b,
                                                    const int* __restrict__ goffs,
                                                    float* __restrict__ hg) {
    __shared__ float red[16][128];
    int g = blockIdx.x;
    int cp = threadIdx.x & 63;
    int j = threadIdx.x >> 6;  // 0..15
    int s = goffs[g], e = goffs[g + 1];
    float a0 = 0.f, a1 = 0.f;
    for (int r = s + j; r < e; r += 16) {
        uint32 u = x2b[(size_t)r * 64 + cp];
        a0 += bflo(u); a1 += bfhi(u);
    }
    red[j][cp * 2] = a0;
    red[j][cp * 2 + 1] = a1;
    __syncthreads();
    if (j == 0) {
        float t0 = 0.f, t1 = 0.f;
#pragma unroll
        for (int jj = 0; jj < 16; jj++) { t0 += red[jj][cp * 2]; t1 += red[jj][cp * 2 + 1]; }
        float cnt = fmaxf((float)(e - s), 1.0f);
        hg[g * 128 + cp * 2] = t0 / cnt;
        hg[g * 128 + cp * 2 + 1] = t1 / cnt;
    }
}

// ---- classifier head: [G,128|64] @ Wc[192,10] + bc ----
__global__ void final_kernel(const float* __restrict__ hg, const float* __restrict__ perm,
                             const float* __restrict__ Wc, const float* __restrict__ bc,
                             float* __restrict__ out, int G) {
    int t = blockIdx.x * blockDim.x + threadIdx.x;
    if (t >= G * 10) return;
    int g = t / 10, c = t % 10;
    float acc = bc[c];
    const float* hrow = hg + g * 128;
#pragma unroll 8
    for (int k = 0; k < 128; k++) acc = fmaf(hrow[k], Wc[k * 10 + c], acc);
    const float* prow = perm + g * 64;
#pragma unroll 8
    for (int p = 0; p < 64; p++) acc = fmaf(prow[p], Wc[(128 + p) * 10 + c], acc);
    out[t] = acc;
}

extern "C" void kernel_launch(void* const* d_in, const int* in_sizes, int n_in,
                              void* d_out, int out_size, void* d_ws, size_t ws_size,
                              hipStream_t stream) {
    const float* h    = (const float*)d_in[0];
    const float* perm = (const float*)d_in[1];
    const float* W1   = (const float*)d_in[2];
    const float* b1   = (const float*)d_in[3];
    const float* W2   = (const float*)d_in[4];
    const float* b2   = (const float*)d_in[5];
    const float* Wc   = (const float*)d_in[6];
    const float* bc   = (const float*)d_in[7];
    const int* src    = (const int*)d_in[8];
    const int* dst    = (const int*)d_in[9];
    const int* gids   = (const int*)d_in[10];
    float* out = (float*)d_out;

    const int N = in_sizes[0] / 128;
    const int E = in_sizes[8];
    const int G = NUM_G, H = 128;
    const int B = (E + PB_EDGES - 1) / PB_EDGES;
    const int NBIN = (N + W_BIN - 1) / W_BIN;

    char* w = (char*)d_ws;
    size_t off = 0;
    auto alloc = [&](size_t bytes) -> void* {
        void* p = w + off;
        off = (off + bytes + 255) & ~(size_t)255;
        return p;
    };
    uint32* xsb   = (uint32*)alloc((size_t)N * H * 2);  // bf16 scaled in; later x2 out
    uint32* aggb  = (uint32*)alloc((size_t)N * H * 2);  // bf16 agg out (both layers)
    uint32* x1b   = (uint32*)alloc((size_t)N * H * 2);  // bf16 layer-1 out
    unsigned short* Wt1 = (unsigned short*)alloc(16384 * 2);
    unsigned short* Wt2 = (unsigned short*)alloc(16384 * 2);
    int*    adj     = (int*)alloc((size_t)E * 4);
    int*    coff    = (int*)alloc((size_t)(N + 1) * 4);
    int*    indeg   = (int*)alloc((size_t)N * 4);
    int*    outdeg  = (int*)alloc((size_t)N * 4);
    float*  nrm_out = (float*)alloc((size_t)N * 4);
    float*  nrm_in  = (float*)alloc((size_t)N * 4);
    int*    goffs   = (int*)alloc((size_t)(G + 1) * 4);
    float*  hg      = (float*)alloc((size_t)G * H * 4);

    // Build temporaries alias aggb (dead until agg_kernel writes it).
    char* tmp = (char*)aggb;
    size_t toff = 0;
    auto talloc = [&](size_t bytes) -> void* {
        void* p = tmp + toff;
        toff = (toff + bytes + 255) & ~(size_t)255;
        return p;
    };
    int2* ebuf   = (int2*)talloc((size_t)E * 8);
    int*  sbuf   = (int*)talloc((size_t)E * 4);
    int*  bh     = (int*)talloc((size_t)2 * B * NBIN * 4);
    int*  curs   = (int*)talloc((size_t)2 * B * NBIN * 4);
    int*  tot    = (int*)talloc((size_t)2 * NBIN * 4);
    int*  bstart = (int*)talloc((size_t)2 * (NBIN + 1) * 4);

    // ---- weight transpose + cast (independent of graph build) ----
    wt_prep<<<128, 256, 0, stream>>>(W1, W2, Wt1, Wt2);

    // ---- atomic-free graph build ----
    p1_hist<<<2 * B, 256, 0, stream>>>(src, dst, E, NBIN, B, bh);
    p2a_tot<<<2 * NBIN, 256, 0, stream>>>(bh, NBIN, B, tot);
    p2b_scan<<<2, 1024, 0, stream>>>(tot, NBIN, E, bstart);
    p2c_cursor<<<2 * NBIN, 512, 0, stream>>>(bh, bstart, NBIN, B, curs);
    p3_scatter<<<2 * B, 256, 0, stream>>>(src, dst, E, NBIN, B, curs, ebuf, sbuf);
    p4_csr<<<NBIN, 256, 0, stream>>>(ebuf, bstart, NBIN, N, E, indeg, coff, adj);
    p4s_outdeg<<<NBIN, 256, 0, stream>>>(sbuf, bstart + (NBIN + 1), N, outdeg);

    goffs_kernel<<<(N + 1 + 255) / 256, 256, 0, stream>>>(gids, N, goffs);
    norm_kernel<<<(N + 255) / 256, 256, 0, stream>>>(outdeg, indeg, nrm_out, nrm_in, N);

    // layer 1
    scale_kernel<<<(N * 16 + 255) / 256, 256, 0, stream>>>(h, nrm_out, xsb, N);
    agg_kernel<<<(N * 16 + 255) / 256, 256, 0, stream>>>(xsb, adj, coff, aggb, N);
    gemm_mfma<<<(N + 63) / 64, 256, 0, stream>>>((const unsigned short*)aggb, Wt1, b1,
                                                 nrm_in, nrm_out,
                                                 (unsigned short*)x1b, N, 1);

    // layer 2 (output bf16 into xsb, which is dead after agg1)
    agg_kernel<<<(N * 16 + 255) / 256, 256, 0, stream>>>(x1b, adj, coff, aggb, N);
    gemm_mfma<<<(N + 63) / 64, 256, 0, stream>>>((const unsigned short*)aggb, Wt2, b2,
                                                 nrm_in, nullptr,
                                                 (unsigned short*)xsb, N, 0);

    // readout
    mean_kernel<<<G, 1024, 0, stream>>>(xsb, goffs, hg);
    final_kernel<<<(G * 10 + 255) / 256, 256, 0, stream>>>(hg, perm, Wc, bc, out, G);
}

// Round 8
// 354.365 us; speedup vs baseline: 2.0178x; 1.1195x over previous
//
#include <hip/hip_runtime.h>

// GCN: 2x GraphConv(norm='both') + per-graph mean + [hg|perm] @ Wc + bc
// N=100000, E=1600000, D=H=128, P=64, C=10, G=128
// R8: agg unroll-4 (4 outstanding gathers/lane), gemm 32 rows/wave,
// launch fusion (18 -> 13 dispatches).

#define NUM_G 128
#define PB_EDGES 4096   // edges per partition block
#define W_BIN 128       // nodes per bin (key>>7)

typedef unsigned int uint32;
typedef short bf16x8 __attribute__((ext_vector_type(8)));
typedef float f32x4 __attribute__((ext_vector_type(4)));

__device__ __forceinline__ float bflo(uint32 u) { return __uint_as_float(u << 16); }
__device__ __forceinline__ float bfhi(uint32 u) { return __uint_as_float(u & 0xffff0000u); }
__device__ __forceinline__ uint32 f2bf_bits(float f) {  // RNE
    uint32 b = __float_as_uint(f);
    return (b + 0x7fffu + ((b >> 16) & 1u)) >> 16;
}
__device__ __forceinline__ uint32 pack2(float a, float b) {
    return f2bf_bits(a) | (f2bf_bits(b) << 16);
}

// ---- P1: per-block LDS histogram of key>>7. pipe0=dst, pipe1=src ----
__global__ __launch_bounds__(256) void p1_hist(const int* __restrict__ src,
                                               const int* __restrict__ dst, int E,
                                               int NBIN, int B, int* __restrict__ bh) {
    __shared__ int hist[1024];
    int b = blockIdx.x;
    int pipe = (b >= B) ? 1 : 0;
    int bb = pipe ? b - B : b;
    const int* key = pipe ? src : dst;
    for (int i = threadIdx.x; i < NBIN; i += 256) hist[i] = 0;
    __syncthreads();
    int base = bb * PB_EDGES;
    for (int c = threadIdx.x; c < PB_EDGES / 4; c += 256) {
        int e = base + c * 4;
        if (e + 3 < E) {
            int4 k4 = *(const int4*)(key + e);
            atomicAdd(&hist[k4.x >> 7], 1);
            atomicAdd(&hist[k4.y >> 7], 1);
            atomicAdd(&hist[k4.z >> 7], 1);
            atomicAdd(&hist[k4.w >> 7], 1);
        } else {
            for (int i = e; i < E && i < e + 4; i++) atomicAdd(&hist[key[i] >> 7], 1);
        }
    }
    __syncthreads();
    int* outp = bh + (size_t)pipe * NBIN * B;
    for (int k = threadIdx.x; k < NBIN; k += 256)
        outp[(size_t)k * B + bb] = hist[k];
}

// ---- P2a: tot[pipe][k] = sum_b bh[pipe][k][b] ----
__global__ __launch_bounds__(256) void p2a_tot(const int* __restrict__ bh, int NBIN, int B,
                                               int* __restrict__ tot) {
    __shared__ int sc[256];
    int k = blockIdx.x % NBIN, pipe = blockIdx.x / NBIN;
    const int* row = bh + (size_t)pipe * NBIN * B + (size_t)k * B;
    int acc = 0;
    for (int b = threadIdx.x; b < B; b += 256) acc += row[b];
    sc[threadIdx.x] = acc;
    __syncthreads();
    for (int o = 128; o > 0; o >>= 1) {
        if (threadIdx.x < o) sc[threadIdx.x] += sc[threadIdx.x + o];
        __syncthreads();
    }
    if (threadIdx.x == 0) tot[pipe * NBIN + k] = sc[0];
}

// ---- P2c: block (pipe,k): base = prefix(tot) inline; write bstart; scan bh over B ----
__global__ __launch_bounds__(512) void p2c_cursor(const int* __restrict__ bh,
                                                  const int* __restrict__ tot,
                                                  int NBIN, int B, int E,
                                                  int* __restrict__ bstart,
                                                  int* __restrict__ curs) {
    __shared__ int sc[512];
    int k = blockIdx.x % NBIN, pipe = blockIdx.x / NBIN;
    int i = threadIdx.x;
    // inline exclusive prefix: base = sum_{k'<k} tot[pipe][k']
    int pacc = 0;
    for (int kk = i; kk < k; kk += 512) pacc += tot[pipe * NBIN + kk];
    sc[i] = pacc;
    __syncthreads();
    for (int o = 256; o > 0; o >>= 1) {
        if (i < o) sc[i] += sc[i + o];
        __syncthreads();
    }
    int base = sc[0];
    __syncthreads();
    if (i == 0) {
        bstart[pipe * (NBIN + 1) + k] = base;
        if (k == 0) bstart[pipe * (NBIN + 1) + NBIN] = E;
    }
    // scan bh[k][*] over B
    const int* row = bh + (size_t)pipe * NBIN * B + (size_t)k * B;
    int v = (i < B) ? row[i] : 0;
    sc[i] = v;
    __syncthreads();
    for (int o = 1; o < 512; o <<= 1) {
        int t = (i >= o) ? sc[i - o] : 0;
        __syncthreads();
        sc[i] += t;
        __syncthreads();
    }
    if (i < B)
        curs[(size_t)pipe * B * NBIN + (size_t)i * NBIN + k] = base + sc[i] - v;
}

// ---- P3: scatter edges into bin-partitioned buffers (LDS cursors) ----
__global__ __launch_bounds__(256) void p3_scatter(const int* __restrict__ src,
                                                  const int* __restrict__ dst, int E,
                                                  int NBIN, int B, const int* __restrict__ curs,
                                                  int2* __restrict__ ebuf, int* __restrict__ sbuf) {
    __shared__ int cur[1024];
    int b = blockIdx.x;
    int pipe = (b >= B) ? 1 : 0;
    int bb = pipe ? b - B : b;
    const int* crow = curs + (size_t)pipe * B * NBIN + (size_t)bb * NBIN;
    for (int i = threadIdx.x; i < NBIN; i += 256) cur[i] = crow[i];
    __syncthreads();
    int base = bb * PB_EDGES;
    if (!pipe) {
        for (int c = threadIdx.x; c < PB_EDGES / 4; c += 256) {
            int e = base + c * 4;
            if (e + 3 < E) {
                int4 s4 = *(const int4*)(src + e);
                int4 d4 = *(const int4*)(dst + e);
                int p;
                p = atomicAdd(&cur[d4.x >> 7], 1); ebuf[p] = make_int2(s4.x, d4.x);
                p = atomicAdd(&cur[d4.y >> 7], 1); ebuf[p] = make_int2(s4.y, d4.y);
                p = atomicAdd(&cur[d4.z >> 7], 1); ebuf[p] = make_int2(s4.z, d4.z);
                p = atomicAdd(&cur[d4.w >> 7], 1); ebuf[p] = make_int2(s4.w, d4.w);
            } else {
                for (int i = e; i < E && i < e + 4; i++) {
                    int s = src[i], d = dst[i];
                    int p = atomicAdd(&cur[d >> 7], 1);
                    ebuf[p] = make_int2(s, d);
                }
            }
        }
    } else {
        for (int c = threadIdx.x; c < PB_EDGES / 4; c += 256) {
            int e = base + c * 4;
            if (e + 3 < E) {
                int4 s4 = *(const int4*)(src + e);
                int p;
                p = atomicAdd(&cur[s4.x >> 7], 1); sbuf[p] = s4.x;
                p = atomicAdd(&cur[s4.y >> 7], 1); sbuf[p] = s4.y;
                p = atomicAdd(&cur[s4.z >> 7], 1); sbuf[p] = s4.z;
                p = atomicAdd(&cur[s4.w >> 7], 1); sbuf[p] = s4.w;
            } else {
                for (int i = e; i < E && i < e + 4; i++) {
                    int s = src[i];
                    int p = atomicAdd(&cur[s >> 7], 1);
                    sbuf[p] = s;
                }
            }
        }
    }
}

// ---- P4 (fused): k<NBIN: per-bin CSR; k>=NBIN: per-bin outdeg ----
__global__ __launch_bounds__(256) void p4_comb(const int2* __restrict__ ebuf,
                                               const int* __restrict__ sbuf,
                                               const int* __restrict__ bstart,
                                               int NBIN, int N, int E,
                                               int* __restrict__ indeg, int* __restrict__ coff,
                                               int* __restrict__ adj, int* __restrict__ outdeg) {
    __shared__ int hist[128];
    __shared__ int sc[128];
    __shared__ int cur[128];
    __shared__ int lsrc[4096];
    int kb = blockIdx.x;
    int tid = threadIdx.x;
    if (kb >= NBIN) {
        // outdeg histogram from partitioned src values
        int k = kb - NBIN;
        const int* bstartS = bstart + (NBIN + 1);
        int s0 = bstartS[k], s1 = bstartS[k + 1];
        if (tid < 128) hist[tid] = 0;
        __syncthreads();
        for (int i = s0 + tid; i < s1; i += 256) atomicAdd(&hist[sbuf[i] & 127], 1);
        __syncthreads();
        if (tid < 128) {
            int node = k * W_BIN + tid;
            if (node < N) outdeg[node] = hist[tid];
        }
        return;
    }
    int k = kb;
    int s0 = bstart[k], s1 = bstart[k + 1];
    int M = s1 - s0;
    if (tid < 128) hist[tid] = 0;
    __syncthreads();
    for (int i = tid; i < M; i += 256) {
        int2 e = ebuf[s0 + i];
        atomicAdd(&hist[e.y & 127], 1);
    }
    __syncthreads();
    if (tid < 128) sc[tid] = hist[tid];
    __syncthreads();
    for (int o = 1; o < 128; o <<= 1) {
        int v = 0;
        if (tid < 128 && tid >= o) v = sc[tid - o];
        __syncthreads();
        if (tid < 128) sc[tid] += v;
        __syncthreads();
    }
    if (tid < 128) {
        int node = k * W_BIN + tid;
        if (node < N) {
            indeg[node] = hist[tid];
            coff[node] = s0 + sc[tid] - hist[tid];
        }
        cur[tid] = sc[tid] - hist[tid];
    }
    if (k == NBIN - 1 && tid == 0) coff[N] = E;
    __syncthreads();
    if (M <= 4096) {
        for (int i = tid; i < M; i += 256) {
            int2 e = ebuf[s0 + i];
            int p = atomicAdd(&cur[e.y & 127], 1);
            lsrc[p] = e.x;
        }
        __syncthreads();
        for (int i = tid; i < M; i += 256) adj[s0 + i] = lsrc[i];
    } else {
        for (int i = tid; i < M; i += 256) {
            int2 e = ebuf[s0 + i];
            int p = atomicAdd(&cur[e.y & 127], 1);
            adj[s0 + p] = e.x;
        }
    }
}

// ---- misc (fused): goffs boundary-detect + degree norms + Wt bf16 transpose ----
__global__ void misc_kernel(const int* __restrict__ gids,
                            const int* __restrict__ outdeg, const int* __restrict__ indeg,
                            const float* __restrict__ W1, const float* __restrict__ W2,
                            int N, int* __restrict__ goffs,
                            float* __restrict__ nrm_out, float* __restrict__ nrm_in,
                            unsigned short* __restrict__ Wt1, unsigned short* __restrict__ Wt2) {
    int i = blockIdx.x * blockDim.x + threadIdx.x;
    if (i <= N) {
        int prev = (i == 0) ? -1 : gids[i - 1];
        int cur = (i == N) ? NUM_G : gids[i];
        for (int g = prev + 1; g <= cur && g <= NUM_G; g++) goffs[g] = i;
    }
    if (i < N) {
        nrm_out[i] = rsqrtf(fmaxf((float)outdeg[i], 1.0f));
        nrm_in[i]  = rsqrtf(fmaxf((float)indeg[i], 1.0f));
    }
    if (i < 32768) {
        int sel = i >> 14;
        int idx = i & 16383;
        int k = idx >> 7, n = idx & 127;
        float v = (sel ? W2 : W1)[idx];
        (sel ? Wt2 : Wt1)[n * 128 + k] = (unsigned short)f2bf_bits(v);
    }
}

// ---- xsb[n] = bf16(h[n] * nrm_out[n]) : 16 lanes/node, 8 elems/lane ----
__global__ void scale_kernel(const float* __restrict__ h, const float* __restrict__ nrm_out,
                             uint32* __restrict__ xsb, int N) {
    int t = blockIdx.x * blockDim.x + threadIdx.x;
    int node = t >> 4, q = t & 15;
    if (node >= N) return;
    float ns = nrm_out[node];
    const float4* hv = (const float4*)(h + (size_t)node * 128 + q * 8);
    float4 a = hv[0], b = hv[1];
    a.x *= ns; a.y *= ns; a.z *= ns; a.w *= ns;
    b.x *= ns; b.y *= ns; b.z *= ns; b.w *= ns;
    uint4 o;
    o.x = pack2(a.x, a.y); o.y = pack2(a.z, a.w);
    o.z = pack2(b.x, b.y); o.w = pack2(b.z, b.w);
    ((uint4*)xsb)[(size_t)node * 16 + q] = o;
}

// ---- aggregation: 16 lanes/node, unroll-4 (4 outstanding 16B gathers/lane) ----
__global__ void agg_kernel(const uint32* __restrict__ xsb, const int* __restrict__ adj,
                           const int* __restrict__ coff, uint32* __restrict__ aggb, int N) {
    int t = blockIdx.x * blockDim.x + threadIdx.x;
    int node = t >> 4;
    int q = t & 15;
    if (node >= N) return;
    int jb = coff[node], je = coff[node + 1];
    float acc[8];
#pragma unroll
    for (int i = 0; i < 8; i++) acc[i] = 0.f;
    const uint4* rows = (const uint4*)xsb;
    int j = jb;
    for (; j + 3 < je; j += 4) {
        int s0 = adj[j], s1 = adj[j + 1], s2 = adj[j + 2], s3 = adj[j + 3];
        uint4 u0 = rows[(size_t)s0 * 16 + q];
        uint4 u1 = rows[(size_t)s1 * 16 + q];
        uint4 u2 = rows[(size_t)s2 * 16 + q];
        uint4 u3 = rows[(size_t)s3 * 16 + q];
        acc[0] += bflo(u0.x); acc[1] += bfhi(u0.x); acc[2] += bflo(u0.y); acc[3] += bfhi(u0.y);
        acc[4] += bflo(u0.z); acc[5] += bfhi(u0.z); acc[6] += bflo(u0.w); acc[7] += bfhi(u0.w);
        acc[0] += bflo(u1.x); acc[1] += bfhi(u1.x); acc[2] += bflo(u1.y); acc[3] += bfhi(u1.y);
        acc[4] += bflo(u1.z); acc[5] += bfhi(u1.z); acc[6] += bflo(u1.w); acc[7] += bfhi(u1.w);
        acc[0] += bflo(u2.x); acc[1] += bfhi(u2.x); acc[2] += bflo(u2.y); acc[3] += bfhi(u2.y);
        acc[4] += bflo(u2.z); acc[5] += bfhi(u2.z); acc[6] += bflo(u2.w); acc[7] += bfhi(u2.w);
        acc[0] += bflo(u3.x); acc[1] += bfhi(u3.x); acc[2] += bflo(u3.y); acc[3] += bfhi(u3.y);
        acc[4] += bflo(u3.z); acc[5] += bfhi(u3.z); acc[6] += bflo(u3.w); acc[7] += bfhi(u3.w);
    }
    for (; j < je; j++) {
        int s = adj[j];
        uint4 u = rows[(size_t)s * 16 + q];
        acc[0] += bflo(u.x); acc[1] += bfhi(u.x); acc[2] += bflo(u.y); acc[3] += bfhi(u.y);
        acc[4] += bflo(u.z); acc[5] += bfhi(u.z); acc[6] += bflo(u.w); acc[7] += bfhi(u.w);
    }
    uint4 o;
    o.x = pack2(acc[0], acc[1]); o.y = pack2(acc[2], acc[3]);
    o.z = pack2(acc[4], acc[5]); o.w = pack2(acc[6], acc[7]);
    ((uint4*)aggb)[(size_t)node * 16 + q] = o;
}

// ---- MFMA GEMM: 4 waves x 32 rows = 128 rows/block; B-frag shared by 2 row-tiles ----
__global__ __launch_bounds__(256) void gemm_mfma(const unsigned short* __restrict__ A,
                                                 const unsigned short* __restrict__ Wtg,
                                                 const float* __restrict__ bias,
                                                 const float* __restrict__ rowscale,
                                                 const float* __restrict__ postscale,
                                                 unsigned short* __restrict__ out,
                                                 int N, int do_relu) {
    __shared__ unsigned short Wl[128 * 136];
    for (int i = threadIdx.x; i < 2048; i += 256) {
        uint4 v = ((const uint4*)Wtg)[i];
        *(uint4*)&Wl[(i >> 4) * 136 + (i & 15) * 8] = v;
    }
    __syncthreads();

    int lane = threadIdx.x & 63;
    int wv = threadIdx.x >> 6;
    int col_l = lane & 15;
    int quad = lane >> 4;
    int r0w = blockIdx.x * 128 + wv * 32;
    if (r0w >= N) return;

    int arow0 = r0w + col_l;        if (arow0 >= N) arow0 = N - 1;
    int arow1 = r0w + 16 + col_l;   if (arow1 >= N) arow1 = N - 1;
    const unsigned short* Ar0 = A + (size_t)arow0 * 128;
    const unsigned short* Ar1 = A + (size_t)arow1 * 128;

    f32x4 acc[2][8];
#pragma unroll
    for (int rt = 0; rt < 2; rt++)
#pragma unroll
        for (int t = 0; t < 8; t++) {
            acc[rt][t][0] = 0.f; acc[rt][t][1] = 0.f;
            acc[rt][t][2] = 0.f; acc[rt][t][3] = 0.f;
        }

#pragma unroll
    for (int kk = 0; kk < 4; kk++) {
        bf16x8 a0 = *(const bf16x8*)(Ar0 + kk * 32 + quad * 8);
        bf16x8 a1 = *(const bf16x8*)(Ar1 + kk * 32 + quad * 8);
        const unsigned short* wb = &Wl[(size_t)col_l * 136 + kk * 32 + quad * 8];
#pragma unroll
        for (int t = 0; t < 8; t++) {
            bf16x8 b = *(const bf16x8*)(wb + (size_t)t * 16 * 136);
            acc[0][t] = __builtin_amdgcn_mfma_f32_16x16x32_bf16(a0, b, acc[0][t], 0, 0, 0);
            acc[1][t] = __builtin_amdgcn_mfma_f32_16x16x32_bf16(a1, b, acc[1][t], 0, 0, 0);
        }
    }

#pragma unroll
    for (int rt = 0; rt < 2; rt++) {
        int rbase = r0w + rt * 16;
        float s[4], p[4];
#pragma unroll
        for (int j = 0; j < 4; j++) {
            int rw = rbase + quad * 4 + j;
            bool ok = rw < N;
            s[j] = ok ? rowscale[ok ? rw : 0] : 0.f;
            p[j] = (postscale != nullptr && ok) ? postscale[rw] : 1.f;
        }
#pragma unroll
        for (int t = 0; t < 8; t++) {
            int c = t * 16 + col_l;
            float bia = bias[c];
#pragma unroll
            for (int j = 0; j < 4; j++) {
                int rw = rbase + quad * 4 + j;
                if (rw >= N) continue;
                float v = fmaf(s[j], acc[rt][t][j], bia);
                if (do_relu) v = fmaxf(v, 0.f);
                v *= p[j];
                out[(size_t)rw * 128 + c] = (unsigned short)f2bf_bits(v);
            }
        }
    }
}

// ---- fused per-graph mean + classifier head ----
__global__ __launch_bounds__(1024) void mean_final(const uint32* __restrict__ x2b,
                                                   const int* __restrict__ goffs,
                                                   const float* __restrict__ perm,
                                                   const float* __restrict__ Wc,
                                                   const float* __restrict__ bc,
                                                   float* __restrict__ out) {
    __shared__ float red[16][128];
    __shared__ float hrow[128];
    int g = blockIdx.x;
    int cp = threadIdx.x & 63;
    int j = threadIdx.x >> 6;  // 0..15
    int s = goffs[g], e = goffs[g + 1];
    float a0 = 0.f, a1 = 0.f;
    for (int r = s + j; r < e; r += 16) {
        uint32 u = x2b[(size_t)r * 64 + cp];
        a0 += bflo(u); a1 += bfhi(u);
    }
    red[j][cp * 2] = a0;
    red[j][cp * 2 + 1] = a1;
    __syncthreads();
    if (j == 0) {
        float t0 = 0.f, t1 = 0.f;
#pragma unroll
        for (int jj = 0; jj < 16; jj++) { t0 += red[jj][cp * 2]; t1 += red[jj][cp * 2 + 1]; }
        float cnt = fmaxf((float)(e - s), 1.0f);
        hrow[cp * 2] = t0 / cnt;
        hrow[cp * 2 + 1] = t1 / cnt;
    }
    __syncthreads();
    if (threadIdx.x < 10) {
        int c = threadIdx.x;
        float acc = bc[c];
#pragma unroll 8
        for (int k = 0; k < 128; k++) acc = fmaf(hrow[k], Wc[k * 10 + c], acc);
        const float* prow = perm + g * 64;
#pragma unroll 8
        for (int p = 0; p < 64; p++) acc = fmaf(prow[p], Wc[(128 + p) * 10 + c], acc);
        out[g * 10 + c] = acc;
    }
}

extern "C" void kernel_launch(void* const* d_in, const int* in_sizes, int n_in,
                              void* d_out, int out_size, void* d_ws, size_t ws_size,
                              hipStream_t stream) {
    const float* h    = (const float*)d_in[0];
    const float* perm = (const float*)d_in[1];
    const float* W1   = (const float*)d_in[2];
    const float* b1   = (const float*)d_in[3];
    const float* W2   = (const float*)d_in[4];
    const float* b2   = (const float*)d_in[5];
    const float* Wc   = (const float*)d_in[6];
    const float* bc   = (const float*)d_in[7];
    const int* src    = (const int*)d_in[8];
    const int* dst    = (const int*)d_in[9];
    const int* gids   = (const int*)d_in[10];
    float* out = (float*)d_out;

    const int N = in_sizes[0] / 128;
    const int E = in_sizes[8];
    const int G = NUM_G, H = 128;
    const int B = (E + PB_EDGES - 1) / PB_EDGES;
    const int NBIN = (N + W_BIN - 1) / W_BIN;

    char* w = (char*)d_ws;
    size_t off = 0;
    auto alloc = [&](size_t bytes) -> void* {
        void* p = w + off;
        off = (off + bytes + 255) & ~(size_t)255;
        return p;
    };
    uint32* xsb   = (uint32*)alloc((size_t)N * H * 2);  // bf16 scaled in; later x2 out
    uint32* aggb  = (uint32*)alloc((size_t)N * H * 2);  // bf16 agg out (both layers)
    uint32* x1b   = (uint32*)alloc((size_t)N * H * 2);  // bf16 layer-1 out
    unsigned short* Wt1 = (unsigned short*)alloc(16384 * 2);
    unsigned short* Wt2 = (unsigned short*)alloc(16384 * 2);
    int*    adj     = (int*)alloc((size_t)E * 4);
    int*    coff    = (int*)alloc((size_t)(N + 1) * 4);
    int*    indeg   = (int*)alloc((size_t)N * 4);
    int*    outdeg  = (int*)alloc((size_t)N * 4);
    float*  nrm_out = (float*)alloc((size_t)N * 4);
    float*  nrm_in  = (float*)alloc((size_t)N * 4);
    int*    goffs   = (int*)alloc((size_t)(G + 1) * 4);

    // Build temporaries alias aggb (dead until agg_kernel writes it).
    char* tmp = (char*)aggb;
    size_t toff = 0;
    auto talloc = [&](size_t bytes) -> void* {
        void* p = tmp + toff;
        toff = (toff + bytes + 255) & ~(size_t)255;
        return p;
    };
    int2* ebuf   = (int2*)talloc((size_t)E * 8);
    int*  sbuf   = (int*)talloc((size_t)E * 4);
    int*  bh     = (int*)talloc((size_t)2 * B * NBIN * 4);
    int*  curs   = (int*)talloc((size_t)2 * B * NBIN * 4);
    int*  tot    = (int*)talloc((size_t)2 * NBIN * 4);
    int*  bstart = (int*)talloc((size_t)2 * (NBIN + 1) * 4);

    // ---- atomic-free graph build ----
    p1_hist<<<2 * B, 256, 0, stream>>>(src, dst, E, NBIN, B, bh);
    p2a_tot<<<2 * NBIN, 256, 0, stream>>>(bh, NBIN, B, tot);
    p2c_cursor<<<2 * NBIN, 512, 0, stream>>>(bh, tot, NBIN, B, E, bstart, curs);
    p3_scatter<<<2 * B, 256, 0, stream>>>(src, dst, E, NBIN, B, curs, ebuf, sbuf);
    p4_comb<<<2 * NBIN, 256, 0, stream>>>(ebuf, sbuf, bstart, NBIN, N, E,
                                          indeg, coff, adj, outdeg);

    misc_kernel<<<(N + 1 + 255) / 256, 256, 0, stream>>>(gids, outdeg, indeg, W1, W2, N,
                                                         goffs, nrm_out, nrm_in, Wt1, Wt2);

    // layer 1
    scale_kernel<<<(N * 16 + 255) / 256, 256, 0, stream>>>(h, nrm_out, xsb, N);
    agg_kernel<<<(N * 16 + 255) / 256, 256, 0, stream>>>(xsb, adj, coff, aggb, N);
    gemm_mfma<<<(N + 127) / 128, 256, 0, stream>>>((const unsigned short*)aggb, Wt1, b1,
                                                   nrm_in, nrm_out,
                                                   (unsigned short*)x1b, N, 1);

    // layer 2 (output bf16 into xsb, dead after agg1)
    agg_kernel<<<(N * 16 + 255) / 256, 256, 0, stream>>>(x1b, adj, coff, aggb, N);
    gemm_mfma<<<(N + 127) / 128, 256, 0, stream>>>((const unsigned short*)aggb, Wt2, b2,
                                                   nrm_in, nullptr,
                                                   (unsigned short*)xsb, N, 0);

    // fused readout
    mean_final<<<G, 1024, 0, stream>>>(xsb, goffs, perm, Wc, bc, out);
}